// Round 4
// baseline (27560.587 us; speedup 1.0000x reference)
//
#include <hip/hip_runtime.h>
#include <hip/hip_bf16.h>

typedef __hip_bfloat16 bf16;

#define NCONS 50000
#define NVARS 50000
#define NEDGE 600000

__device__ __forceinline__ float b2f(const bf16 v){ return __bfloat162float(v); }
__device__ __forceinline__ float shflf(float v, int lane){ return __shfl(v, lane, 64); }

// ---- input-dtype sniffer: bits[14:7] of each u32 = bf16 exponent if data is
// bf16 pairs (concentrated near 0x7F for ~N(0,1) data), uniform mantissa bits
// if data is f32. mode: 1 = bf16 inputs, 0 = f32 inputs. ----
__global__ void detect_k(const unsigned int* __restrict__ x, int* __restrict__ mode){
  int t = threadIdx.x;
  int hits = 0;
  for (int i=0;i<4;++i){
    unsigned w = x[t*4+i];
    unsigned e = (w>>7)&0xFFu;
    if (e >= 0x70u && e <= 0x8Fu) hits++;
  }
  for (int off=32; off>0; off>>=1) hits += __shfl_down(hits, off);
  if (t==0) *mode = (hits > 128) ? 1 : 0;
}

// ---- sentinel: 0x40004000 = 2.00003 as f32, (2.0,2.0) as bf16 pair ----
__global__ void fill_out_k(unsigned int* __restrict__ p){
  int i = blockIdx.x*blockDim.x + threadIdx.x;
  if (i < 25000) p[i] = 0x40004000u;
}

// ---- convert any float input to f32 in workspace (mode-dispatched) ----
__global__ void convert_k(const void* __restrict__ src, float* __restrict__ dst, int n,
                          const int* __restrict__ mode){
  int m = *mode;
  int i = blockIdx.x*blockDim.x + threadIdx.x;
  int stride = gridDim.x*blockDim.x;
  if (m){
    const bf16* s = (const bf16*)src;
    for (; i<n; i+=stride) dst[i] = b2f(s[i]);
  } else {
    const float* s = (const float*)src;
    for (; i<n; i+=stride) dst[i] = s[i];
  }
}

__global__ void zero_k(float* __restrict__ p, int n){
  int i = blockIdx.x*blockDim.x + threadIdx.x;
  int stride = gridDim.x*blockDim.x;
  for (; i<n; i+=stride) p[i] = 0.f;
}

// ---- per-column sums / sumsq for BN folding (cols <= 5, f32 input) ----
__global__ void col_stats_k(const float* __restrict__ x, int rows, int cols, float* __restrict__ sums){
  int tid = blockIdx.x*blockDim.x + threadIdx.x;
  int stride = gridDim.x*blockDim.x;
  float s[5], ss[5];
  for (int c=0;c<5;++c){ s[c]=0.f; ss[c]=0.f; }
  for (int r=tid; r<rows; r+=stride){
    for (int c=0;c<cols;++c){
      float v = x[r*cols+c];
      s[c]+=v; ss[c]+=v*v;
    }
  }
  for (int c=0;c<cols;++c){
    float a=s[c], b=ss[c];
    for (int off=32; off>0; off>>=1){ a+=__shfl_down(a,off); b+=__shfl_down(b,off); }
    if ((threadIdx.x & 63)==0){ atomicAdd(&sums[c],a); atomicAdd(&sums[cols+c],b); }
  }
}

// stats float layout in ST (floats):
// 0: cons s[3],ss[3]  6: var s[5],ss[5]  16: edge s,ss
// 18: consA[3] 21: consB[3]  24: varA[5] 29: varB[5]  34: edgeA 35: edgeB
// 36 + l*256 (l=0..3): conv BN slot {s64, ss64, A64, B64}
// 36 + 1024 + g*256 (g=0..3): graphnorm slot {s64, ss64, A64, B64}
__global__ void fin_input_k(float* __restrict__ st,
                            const float* __restrict__ cw, const float* __restrict__ cb,
                            const float* __restrict__ vw, const float* __restrict__ vb,
                            const float* __restrict__ ew, const float* __restrict__ eb){
  int t = threadIdx.x;
  if (t < 3){
    float m = st[t]/(float)NCONS, q = st[3+t]/(float)NCONS;
    float A = rsqrtf(fmaxf(q - m*m, 0.f) + 1e-5f)*cw[t];
    st[18+t] = A; st[21+t] = cb[t] - m*A;
  } else if (t < 8){
    int c = t-3;
    float m = st[6+c]/(float)NVARS, q = st[11+c]/(float)NVARS;
    float A = rsqrtf(fmaxf(q - m*m, 0.f) + 1e-5f)*vw[c];
    st[24+c] = A; st[29+c] = vb[c] - m*A;
  } else if (t == 8){
    float m = st[16]/(float)NEDGE, q = st[17]/(float)NEDGE;
    float A = rsqrtf(fmaxf(q - m*m, 0.f) + 1e-5f)*ew[0];
    st[34] = A; st[35] = eb[0] - m*A;
  }
}

// ---- embedding: relu(relu(BN(x)@W1+b1)@W2+b2), block(64)=one node ----
__global__ void embed_k(const float* __restrict__ x, int cin,
                        const float* __restrict__ pA, const float* __restrict__ pB,
                        const float* __restrict__ W1, const float* __restrict__ b1,
                        const float* __restrict__ W2, const float* __restrict__ b2,
                        bf16* __restrict__ out, int nn){
  int n = blockIdx.x; if (n>=nn) return;
  int t = threadIdx.x;
  float acc = b1[t];
  for (int k=0;k<cin;++k){
    float xb = x[n*cin+k]*pA[k] + pB[k];
    acc += xb*W1[k*64+t];
  }
  float h1 = fmaxf(acc, 0.f);
  float acc2 = b2[t];
#pragma unroll
  for (int j=0;j<64;++j) acc2 += shflf(h1,j)*W2[j*64+t];
  out[n*64+t] = __float2bfloat16(fmaxf(acc2, 0.f));
}

// ---- edge messages + scatter-add: one wave per edge, lane = channel ----
__global__ void msg_agg_k(const bf16* __restrict__ left, const bf16* __restrict__ right,
                          const int* __restrict__ src, const int* __restrict__ dst,
                          const float* __restrict__ ea, const float* __restrict__ est,
                          const float* __restrict__ W1, const float* __restrict__ b1,
                          const float* __restrict__ W2, const float* __restrict__ b2,
                          float* __restrict__ agg, float* __restrict__ cnt){
  int t = threadIdx.x & 63;
  int w = (blockIdx.x*blockDim.x + threadIdx.x) >> 6;
  int nw = (gridDim.x*blockDim.x) >> 6;
  float bb1 = b1[t], bb2 = b2[t];
  float eA = est[0], eB = est[1];
  for (int e=w; e<NEDGE; e+=nw){
    int sI = src[e], dI = dst[e];
    float l = b2f(left[sI*64+t]);
    float r = b2f(right[dI*64+t]);
    float ef = ea[e]*eA + eB;
    // cat = [right(64), ef, left(64)] ; h1 = relu(cat @ W1 + b1)
    float acc = bb1 + ef*W1[64*64+t];
#pragma unroll
    for (int j=0;j<64;++j) acc += shflf(r,j)*W1[j*64+t];
#pragma unroll
    for (int j=0;j<64;++j) acc += shflf(l,j)*W1[(65+j)*64+t];
    float h1 = fmaxf(acc,0.f);
    float m = bb2;
#pragma unroll
    for (int j=0;j<64;++j) m += shflf(h1,j)*W2[j*64+t];
    atomicAdd(&agg[dI*64+t], m);
    if (t==0) atomicAdd(&cnt[dI], 1.f);
  }
}

// ---- divide by count in place + column stats of mean-agg ----
__global__ void agg_stats_k(float* __restrict__ agg, const float* __restrict__ cnt,
                            float* __restrict__ slot, int nn){
  int c = threadIdx.x & 63;
  int w = (blockIdx.x*blockDim.x + threadIdx.x) >> 6;
  int nw = (gridDim.x*blockDim.x) >> 6;
  float s=0.f, ss=0.f;
  for (int n=w; n<nn; n+=nw){
    float v = agg[n*64+c] / fmaxf(cnt[n], 1.f);
    agg[n*64+c] = v;
    s += v; ss += v*v;
  }
  atomicAdd(&slot[c], s); atomicAdd(&slot[64+c], ss);
}

__global__ void fin_bn_k(float* __restrict__ slot, const float* __restrict__ w,
                         const float* __restrict__ b, float n){
  int c = threadIdx.x;
  float m = slot[c]/n, q = slot[64+c]/n;
  float rs = rsqrtf(fmaxf(q - m*m, 0.f) + 1e-5f) * w[c];
  slot[128+c] = rs;
  slot[192+c] = b[c] - m*rs;
}

// ---- conv output MLP: relu([BN(agg), right] @ oW1 + ob1) @ oW2 + ob2 ----
__global__ void node_mlp_k(const float* __restrict__ agg, const bf16* __restrict__ right,
                           const float* __restrict__ slot,
                           const float* __restrict__ W1, const float* __restrict__ b1,
                           const float* __restrict__ W2, const float* __restrict__ b2,
                           bf16* __restrict__ out, int nn){
  int n = blockIdx.x; if (n>=nn) return;
  int t = threadIdx.x;
  float post = agg[n*64+t]*slot[128+t] + slot[192+t];
  float r = b2f(right[n*64+t]);
  float acc = b1[t];
#pragma unroll
  for (int j=0;j<64;++j) acc += shflf(post,j)*W1[j*64+t];
#pragma unroll
  for (int j=0;j<64;++j) acc += shflf(r,j)*W1[(64+j)*64+t];
  float h1 = fmaxf(acc,0.f);
  float o = b2[t];
#pragma unroll
  for (int j=0;j<64;++j) o += shflf(h1,j)*W2[j*64+t];
  out[n*64+t] = __float2bfloat16(o);
}

// ---- graphnorm stats / finalize / apply ----
__global__ void gn_stats_k(const bf16* __restrict__ x, float* __restrict__ slot, int nn){
  int c = threadIdx.x & 63;
  int w = (blockIdx.x*blockDim.x + threadIdx.x) >> 6;
  int nw = (gridDim.x*blockDim.x) >> 6;
  float s=0.f, ss=0.f;
  for (int n=w;n<nn;n+=nw){ float v=b2f(x[n*64+c]); s+=v; ss+=v*v; }
  atomicAdd(&slot[c],s); atomicAdd(&slot[64+c],ss);
}

__global__ void fin_gn_k(float* __restrict__ slot, const float* __restrict__ w,
                         const float* __restrict__ b, const float* __restrict__ al, float n){
  int c = threadIdx.x;
  float m = slot[c]/n, q = slot[64+c]/n;
  float a = al[c];
  float var = q - 2.f*a*m*m + a*a*m*m;   // E[(x-a*m)^2]
  float A = rsqrtf(fmaxf(var, 0.f) + 1e-5f) * w[c];
  slot[128+c] = A;
  slot[192+c] = b[c] - a*m*A;
}

__global__ void affine_k(bf16* __restrict__ x, const float* __restrict__ slot, int nn){
  int i = blockIdx.x*blockDim.x + threadIdx.x;
  int stride = gridDim.x*blockDim.x;
  int tot = nn*64;
  for (; i<tot; i+=stride){
    int c = i & 63;
    x[i] = __float2bfloat16(b2f(x[i])*slot[128+c] + slot[192+c]);
  }
}

// ---- final MLP: [vf0,vf1,vf2](192) -> 512 -> 128 -> 1 ; 16 nodes/block ----
__global__ void __launch_bounds__(256) final_mlp_k(
    const bf16* __restrict__ vf0, const bf16* __restrict__ vf1, const bf16* __restrict__ vf2,
    const float* __restrict__ W1, const float* __restrict__ B1,
    const float* __restrict__ W2, const float* __restrict__ B2,
    const float* __restrict__ W3, const float* __restrict__ B3,
    void* __restrict__ out, int nn, const int* __restrict__ mode){
  __shared__ __align__(16) float h[16][192];
  __shared__ __align__(16) float h1[16][512];
  __shared__ float h2[16][129];
  int t = threadIdx.x;
  int n0 = blockIdx.x*16;
  for (int i=t; i<16*192; i+=256){
    int n = i/192, j = i - n*192;
    int node = n0+n;
    float v = (j<64) ? b2f(vf0[node*64+j]) : (j<128) ? b2f(vf1[node*64 + (j-64)]) : b2f(vf2[node*64 + (j-128)]);
    h[n][j] = v;
  }
  __syncthreads();
  { // layer 1: cols t and t+256
    float acc0[16], acc1[16];
    float bbA = B1[t], bbB = B1[t+256];
#pragma unroll
    for (int n=0;n<16;++n){ acc0[n]=bbA; acc1[n]=bbB; }
    for (int j4=0;j4<48;++j4){
      float w0[4], w1[4];
#pragma unroll
      for (int q=0;q<4;++q){ w0[q]=W1[(j4*4+q)*512 + t]; w1[q]=W1[(j4*4+q)*512 + t+256]; }
#pragma unroll
      for (int n=0;n<16;++n){
        const float4 hv = *reinterpret_cast<const float4*>(&h[n][j4*4]);
        acc0[n] += hv.x*w0[0]+hv.y*w0[1]+hv.z*w0[2]+hv.w*w0[3];
        acc1[n] += hv.x*w1[0]+hv.y*w1[1]+hv.z*w1[2]+hv.w*w1[3];
      }
    }
#pragma unroll
    for (int n=0;n<16;++n){ h1[n][t]=fmaxf(acc0[n],0.f); h1[n][t+256]=fmaxf(acc1[n],0.f); }
  }
  __syncthreads();
  { // layer 2: col = t&127, node block of 8
    int c = t & 127;
    int nb = (t>>7)*8;
    float acc[8];
    float bb = B2[c];
#pragma unroll
    for (int n=0;n<8;++n) acc[n]=bb;
    for (int j4=0;j4<128;++j4){
      float w[4];
#pragma unroll
      for (int q=0;q<4;++q) w[q]=W2[(j4*4+q)*128 + c];
#pragma unroll
      for (int n=0;n<8;++n){
        const float4 hv = *reinterpret_cast<const float4*>(&h1[nb+n][j4*4]);
        acc[n] += hv.x*w[0]+hv.y*w[1]+hv.z*w[2]+hv.w*w[3];
      }
    }
#pragma unroll
    for (int n=0;n<8;++n) h2[nb+n][c]=fmaxf(acc[n],0.f);
  }
  __syncthreads();
  if (t<16){
    int node = n0+t;
    if (node<nn){
      float acc = B3[0];
      for (int j=0;j<128;++j) acc += h2[t][j]*W3[j];
      if (*mode) ((bf16*)out)[node] = __float2bfloat16(acc);
      else       ((float*)out)[node] = acc;
    }
  }
}

extern "C" void kernel_launch(void* const* d_in, const int* in_sizes, int n_in,
                              void* d_out, int out_size, void* d_ws, size_t ws_size,
                              hipStream_t stream){
  const int* ei = (const int*)d_in[36];
  const int* src_c = ei;            // edge_index[0]: constraint ids
  const int* src_v = ei + NEDGE;    // edge_index[1]: variable ids

  char* ws = (char*)d_ws;
  float* ST = (float*)ws;                       // 4096 floats = 16 KB
  int* MODE = (int*)(ws + 16384);
  // converted-f32 copies of the 36 float inputs, packed after 32 KB:
  float* F[36];
  {
    size_t foff = 32768;
    for (int i=0;i<36;++i){ F[i] = (float*)(ws + foff); foff += (size_t)in_sizes[i]*4; }
  }
  size_t o = 8u*1024*1024;  // fixed region for the big buffers (converts end ~5.2 MB)
  float* AGG = (float*)(ws + o); o += (size_t)NCONS*64*sizeof(float);
  float* CNT = (float*)(ws + o); o += (size_t)NCONS*sizeof(float);
  bf16* CFA = (bf16*)(ws + o); o += (size_t)NCONS*64*sizeof(bf16);
  bf16* CFB = (bf16*)(ws + o); o += (size_t)NCONS*64*sizeof(bf16);
  bf16* VF0 = (bf16*)(ws + o); o += (size_t)NVARS*64*sizeof(bf16);
  bf16* VF1 = (bf16*)(ws + o); o += (size_t)NVARS*64*sizeof(bf16);
  bf16* VF2 = (bf16*)(ws + o); o += (size_t)NVARS*64*sizeof(bf16);
  // total ≈ 53 MB

  detect_k<<<1,64,0,stream>>>((const unsigned int*)d_in[0], MODE);
  fill_out_k<<<98,256,0,stream>>>((unsigned int*)d_out);   // sentinel ≈ 2.0
  for (int i=0;i<36;++i){
    int n = in_sizes[i];
    int g = (n + 255)/256; if (g > 1024) g = 1024;
    convert_k<<<g,256,0,stream>>>(d_in[i], F[i], n, MODE);
  }

  zero_k<<<8,256,0,stream>>>(ST, 4096);
  col_stats_k<<<256,256,0,stream>>>(F[0], NCONS, 3, ST+0);
  col_stats_k<<<256,256,0,stream>>>(F[2], NVARS, 5, ST+6);
  col_stats_k<<<512,256,0,stream>>>(F[1], NEDGE, 1, ST+16);
  fin_input_k<<<1,64,0,stream>>>(ST, F[3], F[4], F[11], F[12], F[9], F[10]);
  embed_k<<<NCONS,64,0,stream>>>(F[0], 3, ST+18, ST+21, F[5], F[6], F[7], F[8], CFA, NCONS);
  embed_k<<<NVARS,64,0,stream>>>(F[2], 5, ST+24, ST+29, F[13], F[14], F[15], F[16], VF0, NVARS);

  const bf16* lefts[4]  = {VF0, CFB, VF1, CFA};
  const bf16* rights[4] = {CFA, VF0, CFB, VF1};
  bf16*       outs[4]   = {CFB, VF1, CFA, VF2};
  const int*  srcs[4]   = {src_v, src_c, src_v, src_c};
  const int*  dsts[4]   = {src_c, src_v, src_c, src_v};

  for (int l=0; l<4; ++l){
    zero_k<<<2048,256,0,stream>>>(AGG, NCONS*64 + NCONS);  // AGG and CNT contiguous
    msg_agg_k<<<2048,256,0,stream>>>(lefts[l], rights[l], srcs[l], dsts[l], F[1], ST+34,
                                     F[17] + (size_t)l*129*64, F[18] + l*64,
                                     F[19] + (size_t)l*64*64, F[20] + l*64, AGG, CNT);
    float* slot = ST + 36 + l*256;
    agg_stats_k<<<128,256,0,stream>>>(AGG, CNT, slot, NCONS);
    fin_bn_k<<<1,64,0,stream>>>(slot, F[21] + l*64, F[22] + l*64, (float)NCONS);
    node_mlp_k<<<NCONS,64,0,stream>>>(AGG, rights[l], slot,
                                      F[23] + (size_t)l*128*64, F[24] + l*64,
                                      F[25] + (size_t)l*64*64, F[26] + l*64, outs[l], NCONS);
    if (l == 1 || l == 3){
      bf16* cfbuf = outs[l-1];
      bf16* vfbuf = outs[l];
      int ga = l-1, gb = l;
      float* gsA = ST + 36 + 1024 + ga*256;
      float* gsB = ST + 36 + 1024 + gb*256;
      gn_stats_k<<<128,256,0,stream>>>(cfbuf, gsA, NCONS);
      fin_gn_k<<<1,64,0,stream>>>(gsA, F[27]+ga*64, F[28]+ga*64, F[29]+ga*64, (float)NCONS);
      affine_k<<<1024,256,0,stream>>>(cfbuf, gsA, NCONS);
      gn_stats_k<<<128,256,0,stream>>>(vfbuf, gsB, NVARS);
      fin_gn_k<<<1,64,0,stream>>>(gsB, F[27]+gb*64, F[28]+gb*64, F[29]+gb*64, (float)NVARS);
      affine_k<<<1024,256,0,stream>>>(vfbuf, gsB, NVARS);
    }
  }
  final_mlp_k<<<(NVARS+15)/16,256,0,stream>>>(VF0, VF1, VF2, F[30], F[31],
                                              F[32], F[33], F[34], F[35],
                                              d_out, NVARS, MODE);
}

// Round 5
// 13382.391 us; speedup vs baseline: 2.0595x; 2.0595x over previous
//
#include <hip/hip_runtime.h>
#include <hip/hip_bf16.h>

typedef __hip_bfloat16 bf16;

#define NCONS 50000
#define NVARS 50000
#define NEDGE 600000

__device__ __forceinline__ float b2f(const bf16 v){ return __bfloat162float(v); }
__device__ __forceinline__ float shflf(float v, int lane){ return __shfl(v, lane, 64); }

// ---- input-dtype sniffer: bits[14:7] of each u32 = bf16 exponent if data is
// bf16 pairs (concentrated near 0x7F for ~N(0,1) data), uniform mantissa bits
// if data is f32. mode: 1 = bf16 inputs, 0 = f32 inputs. ----
__global__ void detect_k(const unsigned int* __restrict__ x, int* __restrict__ mode){
  int t = threadIdx.x;
  int hits = 0;
  for (int i=0;i<4;++i){
    unsigned w = x[t*4+i];
    unsigned e = (w>>7)&0xFFu;
    if (e >= 0x70u && e <= 0x8Fu) hits++;
  }
  for (int off=32; off>0; off>>=1) hits += __shfl_down(hits, off);
  if (t==0) *mode = (hits > 128) ? 1 : 0;
}

// ---- convert any float input to f32 in workspace (mode-dispatched) ----
__global__ void convert_k(const void* __restrict__ src, float* __restrict__ dst, int n,
                          const int* __restrict__ mode){
  int m = *mode;
  int i = blockIdx.x*blockDim.x + threadIdx.x;
  int stride = gridDim.x*blockDim.x;
  if (m){
    const bf16* s = (const bf16*)src;
    for (; i<n; i+=stride) dst[i] = b2f(s[i]);
  } else {
    const float* s = (const float*)src;
    for (; i<n; i+=stride) dst[i] = s[i];
  }
}

__global__ void zero_k(float* __restrict__ p, int n){
  int i = blockIdx.x*blockDim.x + threadIdx.x;
  int stride = gridDim.x*blockDim.x;
  for (; i<n; i+=stride) p[i] = 0.f;
}

// ---- node degrees (once per direction) ----
__global__ void deg_k(const int* __restrict__ dst, float* __restrict__ cnt){
  int i = blockIdx.x*blockDim.x + threadIdx.x;
  int stride = gridDim.x*blockDim.x;
  for (; i<NEDGE; i+=stride) atomicAdd(&cnt[dst[i]], 1.f);
}

// ---- per-column sums / sumsq for BN folding (cols <= 5, f32 input) ----
__global__ void col_stats_k(const float* __restrict__ x, int rows, int cols, float* __restrict__ sums){
  int tid = blockIdx.x*blockDim.x + threadIdx.x;
  int stride = gridDim.x*blockDim.x;
  float s[5], ss[5];
  for (int c=0;c<5;++c){ s[c]=0.f; ss[c]=0.f; }
  for (int r=tid; r<rows; r+=stride){
    for (int c=0;c<cols;++c){
      float v = x[r*cols+c];
      s[c]+=v; ss[c]+=v*v;
    }
  }
  for (int c=0;c<cols;++c){
    float a=s[c], b=ss[c];
    for (int off=32; off>0; off>>=1){ a+=__shfl_down(a,off); b+=__shfl_down(b,off); }
    if ((threadIdx.x & 63)==0){ atomicAdd(&sums[c],a); atomicAdd(&sums[cols+c],b); }
  }
}

// stats float layout in ST (floats):
// 0: cons s[3],ss[3]  6: var s[5],ss[5]  16: edge s,ss
// 18: consA[3] 21: consB[3]  24: varA[5] 29: varB[5]  34: edgeA 35: edgeB
// 36 + l*256 (l=0..3): conv BN slot {s64, ss64, A64, B64}
// 36 + 1024 + g*256 (g=0..3): graphnorm slot {s64, ss64, A64, B64}
__global__ void fin_input_k(float* __restrict__ st,
                            const float* __restrict__ cw, const float* __restrict__ cb,
                            const float* __restrict__ vw, const float* __restrict__ vb,
                            const float* __restrict__ ew, const float* __restrict__ eb){
  int t = threadIdx.x;
  if (t < 3){
    float m = st[t]/(float)NCONS, q = st[3+t]/(float)NCONS;
    float A = rsqrtf(fmaxf(q - m*m, 0.f) + 1e-5f)*cw[t];
    st[18+t] = A; st[21+t] = cb[t] - m*A;
  } else if (t < 8){
    int c = t-3;
    float m = st[6+c]/(float)NVARS, q = st[11+c]/(float)NVARS;
    float A = rsqrtf(fmaxf(q - m*m, 0.f) + 1e-5f)*vw[c];
    st[24+c] = A; st[29+c] = vb[c] - m*A;
  } else if (t == 8){
    float m = st[16]/(float)NEDGE, q = st[17]/(float)NEDGE;
    float A = rsqrtf(fmaxf(q - m*m, 0.f) + 1e-5f)*ew[0];
    st[34] = A; st[35] = eb[0] - m*A;
  }
}

// ---- embedding: relu(relu(BN(x)@W1+b1)@W2+b2), block(64)=one node ----
__global__ void embed_k(const float* __restrict__ x, int cin,
                        const float* __restrict__ pA, const float* __restrict__ pB,
                        const float* __restrict__ W1, const float* __restrict__ b1,
                        const float* __restrict__ W2, const float* __restrict__ b2,
                        bf16* __restrict__ out, int nn){
  int n = blockIdx.x; if (n>=nn) return;
  int t = threadIdx.x;
  float acc = b1[t];
  for (int k=0;k<cin;++k){
    float xb = x[n*cin+k]*pA[k] + pB[k];
    acc += xb*W1[k*64+t];
  }
  float h1 = fmaxf(acc, 0.f);
  float acc2 = b2[t];
#pragma unroll
  for (int j=0;j<64;++j) acc2 += shflf(h1,j)*W2[j*64+t];
  out[n*64+t] = __float2bfloat16(fmaxf(acc2, 0.f));
}

// ---- edge messages + scatter-add: LDS weights, 8 edges per wave ----
__global__ void __launch_bounds__(256) msg_agg_k(
                          const bf16* __restrict__ left, const bf16* __restrict__ right,
                          const int* __restrict__ src, const int* __restrict__ dst,
                          const float* __restrict__ ea, const float* __restrict__ est,
                          const float* __restrict__ W1, const float* __restrict__ b1,
                          const float* __restrict__ W2, const float* __restrict__ b2,
                          float* __restrict__ agg){
  __shared__ float W1L[129*64];
  __shared__ float W2L[64*64];
  for (int i=threadIdx.x; i<129*64; i+=256) W1L[i] = W1[i];
  for (int i=threadIdx.x; i<64*64; i+=256) W2L[i] = W2[i];
  __syncthreads();
  int t = threadIdx.x & 63;
  int w = (blockIdx.x*blockDim.x + threadIdx.x) >> 6;
  int nw = (gridDim.x*blockDim.x) >> 6;
  float bb1 = b1[t], bb2 = b2[t];
  float eA = est[0], eB = est[1];
  float wE = W1L[64*64+t];
  for (int g = w*8; g < NEDGE; g += nw*8){
    int dI[8];
    float l[8], r[8], acc[8];
#pragma unroll
    for (int k=0;k<8;++k){
      int e = g+k; bool v = (e < NEDGE); int ec = v ? e : 0;
      int sI = src[ec]; dI[k] = dst[ec];
      l[k] = b2f(left[sI*64+t]);
      r[k] = b2f(right[dI[k]*64+t]);
      float ef = ea[ec]*eA + eB;
      acc[k] = bb1 + ef*wE;
    }
    // cat = [right(64), ef, left(64)] ; h1 = relu(cat @ W1 + b1)
#pragma unroll
    for (int j=0;j<64;++j){
      float wr = W1L[j*64+t];
      float wl = W1L[(65+j)*64+t];
#pragma unroll
      for (int k=0;k<8;++k)
        acc[k] += shflf(r[k],j)*wr + shflf(l[k],j)*wl;
    }
    float h1[8];
#pragma unroll
    for (int k=0;k<8;++k){ h1[k] = fmaxf(acc[k],0.f); acc[k] = bb2; }
#pragma unroll
    for (int j=0;j<64;++j){
      float wv = W2L[j*64+t];
#pragma unroll
      for (int k=0;k<8;++k) acc[k] += shflf(h1[k],j)*wv;
    }
#pragma unroll
    for (int k=0;k<8;++k){
      int e = g+k;
      if (e < NEDGE) atomicAdd(&agg[dI[k]*64+t], acc[k]);
    }
  }
}

// ---- divide by count in place + column stats of mean-agg ----
__global__ void agg_stats_k(float* __restrict__ agg, const float* __restrict__ cnt,
                            float* __restrict__ slot, int nn){
  int c = threadIdx.x & 63;
  int w = (blockIdx.x*blockDim.x + threadIdx.x) >> 6;
  int nw = (gridDim.x*blockDim.x) >> 6;
  float s=0.f, ss=0.f;
  for (int n=w; n<nn; n+=nw){
    float v = agg[n*64+c] / fmaxf(cnt[n], 1.f);
    agg[n*64+c] = v;
    s += v; ss += v*v;
  }
  atomicAdd(&slot[c], s); atomicAdd(&slot[64+c], ss);
}

__global__ void fin_bn_k(float* __restrict__ slot, const float* __restrict__ w,
                         const float* __restrict__ b, float n){
  int c = threadIdx.x;
  float m = slot[c]/n, q = slot[64+c]/n;
  float rs = rsqrtf(fmaxf(q - m*m, 0.f) + 1e-5f) * w[c];
  slot[128+c] = rs;
  slot[192+c] = b[c] - m*rs;
}

// ---- conv output MLP: LDS weights, 8 nodes per wave ----
__global__ void __launch_bounds__(256) node_mlp_k(
                           const float* __restrict__ agg, const bf16* __restrict__ right,
                           const float* __restrict__ slot,
                           const float* __restrict__ W1, const float* __restrict__ b1,
                           const float* __restrict__ W2, const float* __restrict__ b2,
                           bf16* __restrict__ out, int nn){
  __shared__ float W1L[128*64];
  __shared__ float W2L[64*64];
  for (int i=threadIdx.x; i<128*64; i+=256) W1L[i] = W1[i];
  for (int i=threadIdx.x; i<64*64; i+=256) W2L[i] = W2[i];
  __syncthreads();
  int t = threadIdx.x & 63;
  int w = (blockIdx.x*blockDim.x + threadIdx.x) >> 6;
  int nw = (gridDim.x*blockDim.x) >> 6;
  float sA = slot[128+t], sB = slot[192+t];
  float bb1 = b1[t], bb2 = b2[t];
  for (int g = w*8; g < nn; g += nw*8){
    float post[8], r[8], acc[8];
#pragma unroll
    for (int k=0;k<8;++k){
      int n = g+k; bool v = (n < nn); int nc = v ? n : 0;
      post[k] = v ? (agg[nc*64+t]*sA + sB) : 0.f;
      r[k]    = v ? b2f(right[nc*64+t]) : 0.f;
      acc[k] = bb1;
    }
#pragma unroll
    for (int j=0;j<64;++j){
      float w1 = W1L[j*64+t];
      float w2 = W1L[(64+j)*64+t];
#pragma unroll
      for (int k=0;k<8;++k)
        acc[k] += shflf(post[k],j)*w1 + shflf(r[k],j)*w2;
    }
    float h1[8];
#pragma unroll
    for (int k=0;k<8;++k){ h1[k] = fmaxf(acc[k],0.f); acc[k] = bb2; }
#pragma unroll
    for (int j=0;j<64;++j){
      float wv = W2L[j*64+t];
#pragma unroll
      for (int k=0;k<8;++k) acc[k] += shflf(h1[k],j)*wv;
    }
#pragma unroll
    for (int k=0;k<8;++k){
      int n = g+k;
      if (n < nn) out[n*64+t] = __float2bfloat16(acc[k]);
    }
  }
}

// ---- graphnorm stats / finalize / apply ----
__global__ void gn_stats_k(const bf16* __restrict__ x, float* __restrict__ slot, int nn){
  int c = threadIdx.x & 63;
  int w = (blockIdx.x*blockDim.x + threadIdx.x) >> 6;
  int nw = (gridDim.x*blockDim.x) >> 6;
  float s=0.f, ss=0.f;
  for (int n=w;n<nn;n+=nw){ float v=b2f(x[n*64+c]); s+=v; ss+=v*v; }
  atomicAdd(&slot[c],s); atomicAdd(&slot[64+c],ss);
}

__global__ void fin_gn_k(float* __restrict__ slot, const float* __restrict__ w,
                         const float* __restrict__ b, const float* __restrict__ al, float n){
  int c = threadIdx.x;
  float m = slot[c]/n, q = slot[64+c]/n;
  float a = al[c];
  float var = q - 2.f*a*m*m + a*a*m*m;   // E[(x-a*m)^2]
  float A = rsqrtf(fmaxf(var, 0.f) + 1e-5f) * w[c];
  slot[128+c] = A;
  slot[192+c] = b[c] - a*m*A;
}

__global__ void affine_k(bf16* __restrict__ x, const float* __restrict__ slot, int nn){
  int i = blockIdx.x*blockDim.x + threadIdx.x;
  int stride = gridDim.x*blockDim.x;
  int tot = nn*64;
  for (; i<tot; i+=stride){
    int c = i & 63;
    x[i] = __float2bfloat16(b2f(x[i])*slot[128+c] + slot[192+c]);
  }
}

// ---- final MLP: [vf0,vf1,vf2](192) -> 512 -> 128 -> 1 ; 16 nodes/block ----
__global__ void __launch_bounds__(256) final_mlp_k(
    const bf16* __restrict__ vf0, const bf16* __restrict__ vf1, const bf16* __restrict__ vf2,
    const float* __restrict__ W1, const float* __restrict__ B1,
    const float* __restrict__ W2, const float* __restrict__ B2,
    const float* __restrict__ W3, const float* __restrict__ B3,
    void* __restrict__ out, int nn, const int* __restrict__ mode){
  __shared__ __align__(16) float h[16][192];
  __shared__ __align__(16) float h1[16][512];
  __shared__ float h2[16][129];
  int t = threadIdx.x;
  int n0 = blockIdx.x*16;
  for (int i=t; i<16*192; i+=256){
    int n = i/192, j = i - n*192;
    int node = n0+n;
    float v = (j<64) ? b2f(vf0[node*64+j]) : (j<128) ? b2f(vf1[node*64 + (j-64)]) : b2f(vf2[node*64 + (j-128)]);
    h[n][j] = v;
  }
  __syncthreads();
  { // layer 1: cols t and t+256
    float acc0[16], acc1[16];
    float bbA = B1[t], bbB = B1[t+256];
#pragma unroll
    for (int n=0;n<16;++n){ acc0[n]=bbA; acc1[n]=bbB; }
    for (int j4=0;j4<48;++j4){
      float w0[4], w1[4];
#pragma unroll
      for (int q=0;q<4;++q){ w0[q]=W1[(j4*4+q)*512 + t]; w1[q]=W1[(j4*4+q)*512 + t+256]; }
#pragma unroll
      for (int n=0;n<16;++n){
        const float4 hv = *reinterpret_cast<const float4*>(&h[n][j4*4]);
        acc0[n] += hv.x*w0[0]+hv.y*w0[1]+hv.z*w0[2]+hv.w*w0[3];
        acc1[n] += hv.x*w1[0]+hv.y*w1[1]+hv.z*w1[2]+hv.w*w1[3];
      }
    }
#pragma unroll
    for (int n=0;n<16;++n){ h1[n][t]=fmaxf(acc0[n],0.f); h1[n][t+256]=fmaxf(acc1[n],0.f); }
  }
  __syncthreads();
  { // layer 2: col = t&127, node block of 8
    int c = t & 127;
    int nb = (t>>7)*8;
    float acc[8];
    float bb = B2[c];
#pragma unroll
    for (int n=0;n<8;++n) acc[n]=bb;
    for (int j4=0;j4<128;++j4){
      float w[4];
#pragma unroll
      for (int q=0;q<4;++q) w[q]=W2[(j4*4+q)*128 + c];
#pragma unroll
      for (int n=0;n<8;++n){
        const float4 hv = *reinterpret_cast<const float4*>(&h1[nb+n][j4*4]);
        acc[n] += hv.x*w[0]+hv.y*w[1]+hv.z*w[2]+hv.w*w[3];
      }
    }
#pragma unroll
    for (int n=0;n<8;++n) h2[nb+n][c]=fmaxf(acc[n],0.f);
  }
  __syncthreads();
  if (t<16){
    int node = n0+t;
    if (node<nn){
      float acc = B3[0];
      for (int j=0;j<128;++j) acc += h2[t][j]*W3[j];
      if (*mode) ((bf16*)out)[node] = __float2bfloat16(acc);
      else       ((float*)out)[node] = acc;
    }
  }
}

extern "C" void kernel_launch(void* const* d_in, const int* in_sizes, int n_in,
                              void* d_out, int out_size, void* d_ws, size_t ws_size,
                              hipStream_t stream){
  const int* ei = (const int*)d_in[36];
  const int* src_c = ei;            // edge_index[0]: constraint ids
  const int* src_v = ei + NEDGE;    // edge_index[1]: variable ids

  char* ws = (char*)d_ws;
  float* ST = (float*)ws;                       // 4096 floats = 16 KB
  int* MODE = (int*)(ws + 16384);
  // converted-f32 copies of the 36 float inputs, packed after 32 KB:
  float* F[36];
  {
    size_t foff = 32768;
    for (int i=0;i<36;++i){ F[i] = (float*)(ws + foff); foff += (size_t)in_sizes[i]*4; }
  }
  size_t o = 8u*1024*1024;  // fixed region for the big buffers (converts end ~5.2 MB)
  float* AGG = (float*)(ws + o); o += (size_t)NCONS*64*sizeof(float);
  float* CNTC = (float*)(ws + o); o += (size_t)NCONS*sizeof(float);
  float* CNTV = (float*)(ws + o); o += (size_t)NVARS*sizeof(float);
  bf16* CFA = (bf16*)(ws + o); o += (size_t)NCONS*64*sizeof(bf16);
  bf16* CFB = (bf16*)(ws + o); o += (size_t)NCONS*64*sizeof(bf16);
  bf16* VF0 = (bf16*)(ws + o); o += (size_t)NVARS*64*sizeof(bf16);
  bf16* VF1 = (bf16*)(ws + o); o += (size_t)NVARS*64*sizeof(bf16);
  bf16* VF2 = (bf16*)(ws + o); o += (size_t)NVARS*64*sizeof(bf16);
  // total ≈ 53.5 MB

  detect_k<<<1,64,0,stream>>>((const unsigned int*)d_in[0], MODE);
  for (int i=0;i<36;++i){
    int n = in_sizes[i];
    int g = (n + 255)/256; if (g > 1024) g = 1024;
    convert_k<<<g,256,0,stream>>>(d_in[i], F[i], n, MODE);
  }

  zero_k<<<8,256,0,stream>>>(ST, 4096);
  zero_k<<<128,256,0,stream>>>(CNTC, NCONS + NVARS);   // CNTC,CNTV contiguous
  deg_k<<<1024,256,0,stream>>>(src_c, CNTC);
  deg_k<<<1024,256,0,stream>>>(src_v, CNTV);
  col_stats_k<<<256,256,0,stream>>>(F[0], NCONS, 3, ST+0);
  col_stats_k<<<256,256,0,stream>>>(F[2], NVARS, 5, ST+6);
  col_stats_k<<<512,256,0,stream>>>(F[1], NEDGE, 1, ST+16);
  fin_input_k<<<1,64,0,stream>>>(ST, F[3], F[4], F[11], F[12], F[9], F[10]);
  embed_k<<<NCONS,64,0,stream>>>(F[0], 3, ST+18, ST+21, F[5], F[6], F[7], F[8], CFA, NCONS);
  embed_k<<<NVARS,64,0,stream>>>(F[2], 5, ST+24, ST+29, F[13], F[14], F[15], F[16], VF0, NVARS);

  const bf16* lefts[4]  = {VF0, CFB, VF1, CFA};
  const bf16* rights[4] = {CFA, VF0, CFB, VF1};
  bf16*       outs[4]   = {CFB, VF1, CFA, VF2};
  const int*  srcs[4]   = {src_v, src_c, src_v, src_c};
  const int*  dsts[4]   = {src_c, src_v, src_c, src_v};
  float*      cnts[4]   = {CNTC, CNTV, CNTC, CNTV};

  for (int l=0; l<4; ++l){
    zero_k<<<2048,256,0,stream>>>(AGG, NCONS*64);
    msg_agg_k<<<768,256,0,stream>>>(lefts[l], rights[l], srcs[l], dsts[l], F[1], ST+34,
                                    F[17] + (size_t)l*129*64, F[18] + l*64,
                                    F[19] + (size_t)l*64*64, F[20] + l*64, AGG);
    float* slot = ST + 36 + l*256;
    agg_stats_k<<<128,256,0,stream>>>(AGG, cnts[l], slot, NCONS);
    fin_bn_k<<<1,64,0,stream>>>(slot, F[21] + l*64, F[22] + l*64, (float)NCONS);
    node_mlp_k<<<768,256,0,stream>>>(AGG, rights[l], slot,
                                     F[23] + (size_t)l*128*64, F[24] + l*64,
                                     F[25] + (size_t)l*64*64, F[26] + l*64, outs[l], NCONS);
    if (l == 1 || l == 3){
      bf16* cfbuf = outs[l-1];
      bf16* vfbuf = outs[l];
      int ga = l-1, gb = l;
      float* gsA = ST + 36 + 1024 + ga*256;
      float* gsB = ST + 36 + 1024 + gb*256;
      gn_stats_k<<<128,256,0,stream>>>(cfbuf, gsA, NCONS);
      fin_gn_k<<<1,64,0,stream>>>(gsA, F[27]+ga*64, F[28]+ga*64, F[29]+ga*64, (float)NCONS);
      affine_k<<<1024,256,0,stream>>>(cfbuf, gsA, NCONS);
      gn_stats_k<<<128,256,0,stream>>>(vfbuf, gsB, NVARS);
      fin_gn_k<<<1,64,0,stream>>>(gsB, F[27]+gb*64, F[28]+gb*64, F[29]+gb*64, (float)NVARS);
      affine_k<<<1024,256,0,stream>>>(vfbuf, gsB, NVARS);
    }
  }
  final_mlp_k<<<(NVARS+15)/16,256,0,stream>>>(VF0, VF1, VF2, F[30], F[31],
                                              F[32], F[33], F[34], F[35],
                                              d_out, NVARS, MODE);
}

// Round 6
// 3159.938 us; speedup vs baseline: 8.7219x; 4.2350x over previous
//
#include <hip/hip_runtime.h>
#include <hip/hip_bf16.h>

typedef __hip_bfloat16 bf16;
typedef __attribute__((ext_vector_type(8))) short short8v;
typedef __attribute__((ext_vector_type(4))) float float4v;

#define NCONS 50000
#define NVARS 50000
#define NEDGE 600000

__device__ __forceinline__ float b2f(const bf16 v){ return __bfloat162float(v); }
__device__ __forceinline__ float shflf(float v, int lane){ return __shfl(v, lane, 64); }
__device__ __forceinline__ unsigned short f2b(float v){
  return __builtin_bit_cast(unsigned short, __float2bfloat16(v));
}

// ---- input-dtype sniffer (bf16 pairs vs f32) ----
__global__ void detect_k(const unsigned int* __restrict__ x, int* __restrict__ mode){
  int t = threadIdx.x;
  int hits = 0;
  for (int i=0;i<4;++i){
    unsigned w = x[t*4+i];
    unsigned e = (w>>7)&0xFFu;
    if (e >= 0x70u && e <= 0x8Fu) hits++;
  }
  for (int off=32; off>0; off>>=1) hits += __shfl_down(hits, off);
  if (t==0) *mode = (hits > 128) ? 1 : 0;
}

// ---- convert any float input to f32 in workspace (mode-dispatched) ----
__global__ void convert_k(const void* __restrict__ src, float* __restrict__ dst, int n,
                          const int* __restrict__ mode){
  int m = *mode;
  int i = blockIdx.x*blockDim.x + threadIdx.x;
  int stride = gridDim.x*blockDim.x;
  if (m){
    const bf16* s = (const bf16*)src;
    for (; i<n; i+=stride) dst[i] = b2f(s[i]);
  } else {
    const float* s = (const float*)src;
    for (; i<n; i+=stride) dst[i] = s[i];
  }
}

__global__ void zero_k(float* __restrict__ p, int n){
  int i = blockIdx.x*blockDim.x + threadIdx.x;
  int stride = gridDim.x*blockDim.x;
  for (; i<n; i+=stride) p[i] = 0.f;
}

// ---- node degrees (once per direction) ----
__global__ void deg_k(const int* __restrict__ dst, float* __restrict__ cnt){
  int i = blockIdx.x*blockDim.x + threadIdx.x;
  int stride = gridDim.x*blockDim.x;
  for (; i<NEDGE; i+=stride) atomicAdd(&cnt[dst[i]], 1.f);
}

// ---- per-column sums / sumsq for BN folding ----
__global__ void col_stats_k(const float* __restrict__ x, int rows, int cols, float* __restrict__ sums){
  int tid = blockIdx.x*blockDim.x + threadIdx.x;
  int stride = gridDim.x*blockDim.x;
  float s[5], ss[5];
  for (int c=0;c<5;++c){ s[c]=0.f; ss[c]=0.f; }
  for (int r=tid; r<rows; r+=stride){
    for (int c=0;c<cols;++c){
      float v = x[r*cols+c];
      s[c]+=v; ss[c]+=v*v;
    }
  }
  for (int c=0;c<cols;++c){
    float a=s[c], b=ss[c];
    for (int off=32; off>0; off>>=1){ a+=__shfl_down(a,off); b+=__shfl_down(b,off); }
    if ((threadIdx.x & 63)==0){ atomicAdd(&sums[c],a); atomicAdd(&sums[cols+c],b); }
  }
}

// stats float layout in ST (floats): see round-5 comment (unchanged)
__global__ void fin_input_k(float* __restrict__ st,
                            const float* __restrict__ cw, const float* __restrict__ cb,
                            const float* __restrict__ vw, const float* __restrict__ vb,
                            const float* __restrict__ ew, const float* __restrict__ eb){
  int t = threadIdx.x;
  if (t < 3){
    float m = st[t]/(float)NCONS, q = st[3+t]/(float)NCONS;
    float A = rsqrtf(fmaxf(q - m*m, 0.f) + 1e-5f)*cw[t];
    st[18+t] = A; st[21+t] = cb[t] - m*A;
  } else if (t < 8){
    int c = t-3;
    float m = st[6+c]/(float)NVARS, q = st[11+c]/(float)NVARS;
    float A = rsqrtf(fmaxf(q - m*m, 0.f) + 1e-5f)*vw[c];
    st[24+c] = A; st[29+c] = vb[c] - m*A;
  } else if (t == 8){
    float m = st[16]/(float)NEDGE, q = st[17]/(float)NEDGE;
    float A = rsqrtf(fmaxf(q - m*m, 0.f) + 1e-5f)*ew[0];
    st[34] = A; st[35] = eb[0] - m*A;
  }
}

// ---- embedding: relu(relu(BN(x)@W1+b1)@W2+b2), block(64)=one node ----
__global__ void embed_k(const float* __restrict__ x, int cin,
                        const float* __restrict__ pA, const float* __restrict__ pB,
                        const float* __restrict__ W1, const float* __restrict__ b1,
                        const float* __restrict__ W2, const float* __restrict__ b2,
                        bf16* __restrict__ out, int nn){
  int n = blockIdx.x; if (n>=nn) return;
  int t = threadIdx.x;
  float acc = b1[t];
  for (int k=0;k<cin;++k){
    float xb = x[n*cin+k]*pA[k] + pB[k];
    acc += xb*W1[k*64+t];
  }
  float h1 = fmaxf(acc, 0.f);
  float acc2 = b2[t];
#pragma unroll
  for (int j=0;j<64;++j) acc2 += shflf(h1,j)*W2[j*64+t];
  out[n*64+t] = __float2bfloat16(fmaxf(acc2, 0.f));
}

// ---- weight fragmenter: f32 row-major [rows][64] -> bf16 MFMA B-fragments
// layout [kc][n][lane][8]; lane holds col=n*16+(lane&15), k=kc*32+(lane>>4)*8+j.
// skiprow>=0: source rows >= skiprow shift by +1 (skip the ef row of W1). ----
__global__ void frag_k(const float* __restrict__ Wsrc, unsigned short* __restrict__ Wdst,
                       int kchunks, int skiprow){
  int i = blockIdx.x*blockDim.x + threadIdx.x;
  int tot = kchunks*4*64*8;
  if (i>=tot) return;
  int j = i & 7, lane = (i>>3)&63, n = (i>>9)&3, kc = i>>11;
  int k = kc*32 + (lane>>4)*8 + j;
  int col = n*16 + (lane&15);
  int srcrow = (skiprow>=0 && k>=skiprow) ? k+1 : k;
  Wdst[i] = f2b(Wsrc[srcrow*64 + col]);
}

// ---- MFMA edge-message kernel: 16 edges per wave-iteration.
// h1 = relu([right,ef,left] @ W1 + b1) via 16 MFMA (ef folded into C-init);
// msg = h1 @ W2 + b2 via 8 MFMA; scatter-add f32 atomics. ----
__global__ void __launch_bounds__(256) msg_mfma_k(
    const bf16* __restrict__ left, const bf16* __restrict__ right,
    const int* __restrict__ src, const int* __restrict__ dst,
    const float* __restrict__ ea, const float* __restrict__ est,
    const unsigned short* __restrict__ W1F, const unsigned short* __restrict__ W2F,
    const float* __restrict__ b1, const float* __restrict__ w1e, const float* __restrict__ b2,
    float* __restrict__ agg)
{
  __shared__ __align__(16) unsigned short w1l[8192];        // 4kc x 4n x 64 x 8
  __shared__ __align__(16) unsigned short w2l[4096];        // 2kc x 4n x 64 x 8
  __shared__ __align__(16) unsigned short h1l[4][16*72];    // per-wave h1 tile, stride 72
  {
    const float4* s1 = (const float4*)W1F; float4* d1 = (float4*)w1l;
    for (int i=threadIdx.x; i<1024; i+=256) d1[i] = s1[i];
    const float4* s2 = (const float4*)W2F; float4* d2 = (float4*)w2l;
    for (int i=threadIdx.x; i<512; i+=256) d2[i] = s2[i];
  }
  __syncthreads();
  const short8v* W1v = (const short8v*)w1l;
  const short8v* W2v = (const short8v*)w2l;
  const unsigned short* rgt = (const unsigned short*)right;
  const unsigned short* lft = (const unsigned short*)left;
  int t = threadIdx.x & 63;
  int wv = threadIdx.x >> 6;
  int gw = (blockIdx.x*blockDim.x + threadIdx.x) >> 6;
  int nw = (gridDim.x*blockDim.x) >> 6;
  int r16 = t & 15, kg = t >> 4;
  float eA = est[0], eB = est[1];
  float bb1[4], we[4], bb2[4];
#pragma unroll
  for (int n=0;n<4;++n){ bb1[n]=b1[n*16+r16]; we[n]=w1e[n*16+r16]; bb2[n]=b2[n*16+r16]; }
  unsigned short* h1w = &h1l[wv][0];

  // NEDGE % 16 == 0: no tail guards needed
  for (int g = gw*16; g < NEDGE; g += nw*16){
    int e = g + r16;
    int dI = dst[e], sI = src[e];
    float ef = ea[e]*eA + eB;
    // A-fragments straight from the feature gathers (lane: edge=r16, k=kg*8+j)
    short8v ar0 = *(const short8v*)(rgt + (size_t)dI*64 + kg*8);
    short8v ar1 = *(const short8v*)(rgt + (size_t)dI*64 + 32 + kg*8);
    short8v al0 = *(const short8v*)(lft + (size_t)sI*64 + kg*8);
    short8v al1 = *(const short8v*)(lft + (size_t)sI*64 + 32 + kg*8);
    float efr[4]; int dIr[4];
#pragma unroll
    for (int r=0;r<4;++r){ efr[r]=shflf(ef, kg*4+r); dIr[r]=__shfl(dI, kg*4+r, 64); }
    // layer 1: C-init = b1[col] + ef[row]*W1[64][col]; rows owned: kg*4+r
    float4v c[4];
#pragma unroll
    for (int n=0;n<4;++n){
#pragma unroll
      for (int r=0;r<4;++r) c[n][r] = bb1[n] + efr[r]*we[n];
    }
#pragma unroll
    for (int n=0;n<4;++n){
      c[n] = __builtin_amdgcn_mfma_f32_16x16x32_bf16(ar0, W1v[( 0+n)*64+t], c[n], 0,0,0);
      c[n] = __builtin_amdgcn_mfma_f32_16x16x32_bf16(ar1, W1v[( 4+n)*64+t], c[n], 0,0,0);
      c[n] = __builtin_amdgcn_mfma_f32_16x16x32_bf16(al0, W1v[( 8+n)*64+t], c[n], 0,0,0);
      c[n] = __builtin_amdgcn_mfma_f32_16x16x32_bf16(al1, W1v[(12+n)*64+t], c[n], 0,0,0);
    }
    // relu -> bf16 -> per-wave LDS tile (row=kg*4+r, col=n*16+r16)
#pragma unroll
    for (int n=0;n<4;++n){
#pragma unroll
      for (int r=0;r<4;++r)
        h1w[(kg*4+r)*72 + n*16 + r16] = f2b(fmaxf(c[n][r], 0.f));
    }
    asm volatile("s_waitcnt lgkmcnt(0)" ::: "memory");  // writes visible before transpose read
    // layer 2: A from LDS (lane: edge=r16, k=kg*8+j)
    short8v a20 = *(const short8v*)(h1w + r16*72 + kg*8);
    short8v a21 = *(const short8v*)(h1w + r16*72 + 32 + kg*8);
    float4v d[4];
#pragma unroll
    for (int n=0;n<4;++n) d[n] = (float4v){bb2[n],bb2[n],bb2[n],bb2[n]};
#pragma unroll
    for (int n=0;n<4;++n){
      d[n] = __builtin_amdgcn_mfma_f32_16x16x32_bf16(a20, W2v[(0+n)*64+t], d[n], 0,0,0);
      d[n] = __builtin_amdgcn_mfma_f32_16x16x32_bf16(a21, W2v[(4+n)*64+t], d[n], 0,0,0);
    }
    // scatter-add: lane owns rows kg*4+r, col n*16+r16
#pragma unroll
    for (int r=0;r<4;++r){
      float* ap = agg + (size_t)dIr[r]*64 + r16;
#pragma unroll
      for (int n=0;n<4;++n) atomicAdd(ap + n*16, d[n][r]);
    }
  }
}

// ---- divide by count in place + column stats of mean-agg ----
__global__ void agg_stats_k(float* __restrict__ agg, const float* __restrict__ cnt,
                            float* __restrict__ slot, int nn){
  int c = threadIdx.x & 63;
  int w = (blockIdx.x*blockDim.x + threadIdx.x) >> 6;
  int nw = (gridDim.x*blockDim.x) >> 6;
  float s=0.f, ss=0.f;
  for (int n=w; n<nn; n+=nw){
    float v = agg[n*64+c] / fmaxf(cnt[n], 1.f);
    agg[n*64+c] = v;
    s += v; ss += v*v;
  }
  atomicAdd(&slot[c], s); atomicAdd(&slot[64+c], ss);
}

__global__ void fin_bn_k(float* __restrict__ slot, const float* __restrict__ w,
                         const float* __restrict__ b, float n){
  int c = threadIdx.x;
  float m = slot[c]/n, q = slot[64+c]/n;
  float rs = rsqrtf(fmaxf(q - m*m, 0.f) + 1e-5f) * w[c];
  slot[128+c] = rs;
  slot[192+c] = b[c] - m*rs;
}

// ---- conv output MLP: LDS weights, 8 nodes per wave ----
__global__ void __launch_bounds__(256) node_mlp_k(
                           const float* __restrict__ agg, const bf16* __restrict__ right,
                           const float* __restrict__ slot,
                           const float* __restrict__ W1, const float* __restrict__ b1,
                           const float* __restrict__ W2, const float* __restrict__ b2,
                           bf16* __restrict__ out, int nn){
  __shared__ float W1L[128*64];
  __shared__ float W2L[64*64];
  for (int i=threadIdx.x; i<128*64; i+=256) W1L[i] = W1[i];
  for (int i=threadIdx.x; i<64*64; i+=256) W2L[i] = W2[i];
  __syncthreads();
  int t = threadIdx.x & 63;
  int w = (blockIdx.x*blockDim.x + threadIdx.x) >> 6;
  int nw = (gridDim.x*blockDim.x) >> 6;
  float sA = slot[128+t], sB = slot[192+t];
  float bb1 = b1[t], bb2 = b2[t];
  for (int g = w*8; g < nn; g += nw*8){
    float post[8], r[8], acc[8];
#pragma unroll
    for (int k=0;k<8;++k){
      int n = g+k; bool v = (n < nn); int nc = v ? n : 0;
      post[k] = v ? (agg[nc*64+t]*sA + sB) : 0.f;
      r[k]    = v ? b2f(right[nc*64+t]) : 0.f;
      acc[k] = bb1;
    }
#pragma unroll
    for (int j=0;j<64;++j){
      float w1 = W1L[j*64+t];
      float w2 = W1L[(64+j)*64+t];
#pragma unroll
      for (int k=0;k<8;++k)
        acc[k] += shflf(post[k],j)*w1 + shflf(r[k],j)*w2;
    }
    float h1[8];
#pragma unroll
    for (int k=0;k<8;++k){ h1[k] = fmaxf(acc[k],0.f); acc[k] = bb2; }
#pragma unroll
    for (int j=0;j<64;++j){
      float wv = W2L[j*64+t];
#pragma unroll
      for (int k=0;k<8;++k) acc[k] += shflf(h1[k],j)*wv;
    }
#pragma unroll
    for (int k=0;k<8;++k){
      int n = g+k;
      if (n < nn) out[n*64+t] = __float2bfloat16(acc[k]);
    }
  }
}

// ---- graphnorm stats / finalize / apply ----
__global__ void gn_stats_k(const bf16* __restrict__ x, float* __restrict__ slot, int nn){
  int c = threadIdx.x & 63;
  int w = (blockIdx.x*blockDim.x + threadIdx.x) >> 6;
  int nw = (gridDim.x*blockDim.x) >> 6;
  float s=0.f, ss=0.f;
  for (int n=w;n<nn;n+=nw){ float v=b2f(x[n*64+c]); s+=v; ss+=v*v; }
  atomicAdd(&slot[c],s); atomicAdd(&slot[64+c],ss);
}

__global__ void fin_gn_k(float* __restrict__ slot, const float* __restrict__ w,
                         const float* __restrict__ b, const float* __restrict__ al, float n){
  int c = threadIdx.x;
  float m = slot[c]/n, q = slot[64+c]/n;
  float a = al[c];
  float var = q - 2.f*a*m*m + a*a*m*m;   // E[(x-a*m)^2]
  float A = rsqrtf(fmaxf(var, 0.f) + 1e-5f) * w[c];
  slot[128+c] = A;
  slot[192+c] = b[c] - a*m*A;
}

__global__ void affine_k(bf16* __restrict__ x, const float* __restrict__ slot, int nn){
  int i = blockIdx.x*blockDim.x + threadIdx.x;
  int stride = gridDim.x*blockDim.x;
  int tot = nn*64;
  for (; i<tot; i+=stride){
    int c = i & 63;
    x[i] = __float2bfloat16(b2f(x[i])*slot[128+c] + slot[192+c]);
  }
}

// ---- final MLP: [vf0,vf1,vf2](192) -> 512 -> 128 -> 1 ; 16 nodes/block ----
__global__ void __launch_bounds__(256) final_mlp_k(
    const bf16* __restrict__ vf0, const bf16* __restrict__ vf1, const bf16* __restrict__ vf2,
    const float* __restrict__ W1, const float* __restrict__ B1,
    const float* __restrict__ W2, const float* __restrict__ B2,
    const float* __restrict__ W3, const float* __restrict__ B3,
    void* __restrict__ out, int nn, const int* __restrict__ mode){
  __shared__ __align__(16) float h[16][192];
  __shared__ __align__(16) float h1[16][512];
  __shared__ float h2[16][129];
  int t = threadIdx.x;
  int n0 = blockIdx.x*16;
  for (int i=t; i<16*192; i+=256){
    int n = i/192, j = i - n*192;
    int node = n0+n;
    float v = (j<64) ? b2f(vf0[node*64+j]) : (j<128) ? b2f(vf1[node*64 + (j-64)]) : b2f(vf2[node*64 + (j-128)]);
    h[n][j] = v;
  }
  __syncthreads();
  { // layer 1: cols t and t+256
    float acc0[16], acc1[16];
    float bbA = B1[t], bbB = B1[t+256];
#pragma unroll
    for (int n=0;n<16;++n){ acc0[n]=bbA; acc1[n]=bbB; }
    for (int j4=0;j4<48;++j4){
      float w0[4], w1[4];
#pragma unroll
      for (int q=0;q<4;++q){ w0[q]=W1[(j4*4+q)*512 + t]; w1[q]=W1[(j4*4+q)*512 + t+256]; }
#pragma unroll
      for (int n=0;n<16;++n){
        const float4 hv = *reinterpret_cast<const float4*>(&h[n][j4*4]);
        acc0[n] += hv.x*w0[0]+hv.y*w0[1]+hv.z*w0[2]+hv.w*w0[3];
        acc1[n] += hv.x*w1[0]+hv.y*w1[1]+hv.z*w1[2]+hv.w*w1[3];
      }
    }
#pragma unroll
    for (int n=0;n<16;++n){ h1[n][t]=fmaxf(acc0[n],0.f); h1[n][t+256]=fmaxf(acc1[n],0.f); }
  }
  __syncthreads();
  { // layer 2: col = t&127, node block of 8
    int c = t & 127;
    int nb = (t>>7)*8;
    float acc[8];
    float bb = B2[c];
#pragma unroll
    for (int n=0;n<8;++n) acc[n]=bb;
    for (int j4=0;j4<128;++j4){
      float w[4];
#pragma unroll
      for (int q=0;q<4;++q) w[q]=W2[(j4*4+q)*128 + c];
#pragma unroll
      for (int n=0;n<8;++n){
        const float4 hv = *reinterpret_cast<const float4*>(&h1[nb+n][j4*4]);
        acc[n] += hv.x*w[0]+hv.y*w[1]+hv.z*w[2]+hv.w*w[3];
      }
    }
#pragma unroll
    for (int n=0;n<8;++n) h2[nb+n][c]=fmaxf(acc[n],0.f);
  }
  __syncthreads();
  if (t<16){
    int node = n0+t;
    if (node<nn){
      float acc = B3[0];
      for (int j=0;j<128;++j) acc += h2[t][j]*W3[j];
      if (*mode) ((bf16*)out)[node] = __float2bfloat16(acc);
      else       ((float*)out)[node] = acc;
    }
  }
}

extern "C" void kernel_launch(void* const* d_in, const int* in_sizes, int n_in,
                              void* d_out, int out_size, void* d_ws, size_t ws_size,
                              hipStream_t stream){
  const int* ei = (const int*)d_in[36];
  const int* src_c = ei;            // edge_index[0]: constraint ids
  const int* src_v = ei + NEDGE;    // edge_index[1]: variable ids

  char* ws = (char*)d_ws;
  float* ST = (float*)ws;                       // 4096 floats = 16 KB
  int* MODE = (int*)(ws + 16384);
  // converted-f32 copies of the 36 float inputs, packed after 32 KB (~5.4 MB):
  float* F[36];
  {
    size_t foff = 32768;
    for (int i=0;i<36;++i){ F[i] = (float*)(ws + foff); foff += (size_t)in_sizes[i]*4; }
  }
  // bf16 MFMA weight fragments at 7 MB (96 KB)
  unsigned short* W1Fb = (unsigned short*)(ws + 7u*1024*1024);       // 4 x 8192
  unsigned short* W2Fb = W1Fb + 4*8192;                              // 4 x 4096
  size_t o = 8u*1024*1024;
  float* AGG = (float*)(ws + o); o += (size_t)NCONS*64*sizeof(float);
  float* CNTC = (float*)(ws + o); o += (size_t)NCONS*sizeof(float);
  float* CNTV = (float*)(ws + o); o += (size_t)NVARS*sizeof(float);
  bf16* CFA = (bf16*)(ws + o); o += (size_t)NCONS*64*sizeof(bf16);
  bf16* CFB = (bf16*)(ws + o); o += (size_t)NCONS*64*sizeof(bf16);
  bf16* VF0 = (bf16*)(ws + o); o += (size_t)NVARS*64*sizeof(bf16);
  bf16* VF1 = (bf16*)(ws + o); o += (size_t)NVARS*64*sizeof(bf16);
  bf16* VF2 = (bf16*)(ws + o); o += (size_t)NVARS*64*sizeof(bf16);

  detect_k<<<1,64,0,stream>>>((const unsigned int*)d_in[0], MODE);
  for (int i=0;i<36;++i){
    int n = in_sizes[i];
    int g = (n + 255)/256; if (g > 1024) g = 1024;
    convert_k<<<g,256,0,stream>>>(d_in[i], F[i], n, MODE);
  }
  // pre-fragment conv weights to bf16 MFMA B-layout
  for (int l=0; l<4; ++l){
    frag_k<<<32,256,0,stream>>>(F[17] + (size_t)l*129*64, W1Fb + l*8192, 4, 64);
    frag_k<<<16,256,0,stream>>>(F[19] + (size_t)l*64*64,  W2Fb + l*4096, 2, -1);
  }

  zero_k<<<8,256,0,stream>>>(ST, 4096);
  zero_k<<<128,256,0,stream>>>(CNTC, NCONS + NVARS);   // CNTC,CNTV contiguous
  deg_k<<<1024,256,0,stream>>>(src_c, CNTC);
  deg_k<<<1024,256,0,stream>>>(src_v, CNTV);
  col_stats_k<<<256,256,0,stream>>>(F[0], NCONS, 3, ST+0);
  col_stats_k<<<256,256,0,stream>>>(F[2], NVARS, 5, ST+6);
  col_stats_k<<<512,256,0,stream>>>(F[1], NEDGE, 1, ST+16);
  fin_input_k<<<1,64,0,stream>>>(ST, F[3], F[4], F[11], F[12], F[9], F[10]);
  embed_k<<<NCONS,64,0,stream>>>(F[0], 3, ST+18, ST+21, F[5], F[6], F[7], F[8], CFA, NCONS);
  embed_k<<<NVARS,64,0,stream>>>(F[2], 5, ST+24, ST+29, F[13], F[14], F[15], F[16], VF0, NVARS);

  const bf16* lefts[4]  = {VF0, CFB, VF1, CFA};
  const bf16* rights[4] = {CFA, VF0, CFB, VF1};
  bf16*       outs[4]   = {CFB, VF1, CFA, VF2};
  const int*  srcs[4]   = {src_v, src_c, src_v, src_c};
  const int*  dsts[4]   = {src_c, src_v, src_c, src_v};
  float*      cnts[4]   = {CNTC, CNTV, CNTC, CNTV};

  for (int l=0; l<4; ++l){
    zero_k<<<2048,256,0,stream>>>(AGG, NCONS*64);
    msg_mfma_k<<<1024,256,0,stream>>>(lefts[l], rights[l], srcs[l], dsts[l], F[1], ST+34,
                                      W1Fb + l*8192, W2Fb + l*4096,
                                      F[18] + l*64,
                                      F[17] + (size_t)l*129*64 + 64*64,   // W1 row 64 (ef weights)
                                      F[20] + l*64, AGG);
    float* slot = ST + 36 + l*256;
    agg_stats_k<<<128,256,0,stream>>>(AGG, cnts[l], slot, NCONS);
    fin_bn_k<<<1,64,0,stream>>>(slot, F[21] + l*64, F[22] + l*64, (float)NCONS);
    node_mlp_k<<<768,256,0,stream>>>(AGG, rights[l], slot,
                                     F[23] + (size_t)l*128*64, F[24] + l*64,
                                     F[25] + (size_t)l*64*64, F[26] + l*64, outs[l], NCONS);
    if (l == 1 || l == 3){
      bf16* cfbuf = outs[l-1];
      bf16* vfbuf = outs[l];
      int ga = l-1, gb = l;
      float* gsA = ST + 36 + 1024 + ga*256;
      float* gsB = ST + 36 + 1024 + gb*256;
      gn_stats_k<<<128,256,0,stream>>>(cfbuf, gsA, NCONS);
      fin_gn_k<<<1,64,0,stream>>>(gsA, F[27]+ga*64, F[28]+ga*64, F[29]+ga*64, (float)NCONS);
      affine_k<<<1024,256,0,stream>>>(cfbuf, gsA, NCONS);
      gn_stats_k<<<128,256,0,stream>>>(vfbuf, gsB, NVARS);
      fin_gn_k<<<1,64,0,stream>>>(gsB, F[27]+gb*64, F[28]+gb*64, F[29]+gb*64, (float)NVARS);
      affine_k<<<1024,256,0,stream>>>(vfbuf, gsB, NVARS);
    }
  }
  final_mlp_k<<<(NVARS+15)/16,256,0,stream>>>(VF0, VF1, VF2, F[30], F[31],
                                              F[32], F[33], F[34], F[35],
                                              d_out, NVARS, MODE);
}

// Round 7
// 1811.620 us; speedup vs baseline: 15.2132x; 1.7443x over previous
//
#include <hip/hip_runtime.h>
#include <hip/hip_bf16.h>

typedef __hip_bfloat16 bf16;
typedef __attribute__((ext_vector_type(8))) short short8v;
typedef __attribute__((ext_vector_type(4))) float float4v;

#define NCONS 50000
#define NVARS 50000
#define NEDGE 600000

__device__ __forceinline__ float b2f(const bf16 v){ return __bfloat162float(v); }
__device__ __forceinline__ float shflf(float v, int lane){ return __shfl(v, lane, 64); }
__device__ __forceinline__ unsigned short f2b(float v){
  return __builtin_bit_cast(unsigned short, __float2bfloat16(v));
}

// ---- input-dtype sniffer (bf16 pairs vs f32) ----
__global__ void detect_k(const unsigned int* __restrict__ x, int* __restrict__ mode){
  int t = threadIdx.x;
  int hits = 0;
  for (int i=0;i<4;++i){
    unsigned w = x[t*4+i];
    unsigned e = (w>>7)&0xFFu;
    if (e >= 0x70u && e <= 0x8Fu) hits++;
  }
  for (int off=32; off>0; off>>=1) hits += __shfl_down(hits, off);
  if (t==0) *mode = (hits > 128) ? 1 : 0;
}

// ---- convert any float input to f32 in workspace (mode-dispatched) ----
__global__ void convert_k(const void* __restrict__ src, float* __restrict__ dst, int n,
                          const int* __restrict__ mode){
  int m = *mode;
  int i = blockIdx.x*blockDim.x + threadIdx.x;
  int stride = gridDim.x*blockDim.x;
  if (m){
    const bf16* s = (const bf16*)src;
    for (; i<n; i+=stride) dst[i] = b2f(s[i]);
  } else {
    const float* s = (const float*)src;
    for (; i<n; i+=stride) dst[i] = s[i];
  }
}

__global__ void zero_k(float* __restrict__ p, int n){
  int i = blockIdx.x*blockDim.x + threadIdx.x;
  int stride = gridDim.x*blockDim.x;
  for (; i<n; i+=stride) p[i] = 0.f;
}

// ---- node degrees (once per direction) ----
__global__ void deg_k(const int* __restrict__ dst, float* __restrict__ cnt){
  int i = blockIdx.x*blockDim.x + threadIdx.x;
  int stride = gridDim.x*blockDim.x;
  for (; i<NEDGE; i+=stride) atomicAdd(&cnt[dst[i]], 1.f);
}

// ---- per-column sums / sumsq for BN folding ----
__global__ void col_stats_k(const float* __restrict__ x, int rows, int cols, float* __restrict__ sums){
  int tid = blockIdx.x*blockDim.x + threadIdx.x;
  int stride = gridDim.x*blockDim.x;
  float s[5], ss[5];
  for (int c=0;c<5;++c){ s[c]=0.f; ss[c]=0.f; }
  for (int r=tid; r<rows; r+=stride){
    for (int c=0;c<cols;++c){
      float v = x[r*cols+c];
      s[c]+=v; ss[c]+=v*v;
    }
  }
  for (int c=0;c<cols;++c){
    float a=s[c], b=ss[c];
    for (int off=32; off>0; off>>=1){ a+=__shfl_down(a,off); b+=__shfl_down(b,off); }
    if ((threadIdx.x & 63)==0){ atomicAdd(&sums[c],a); atomicAdd(&sums[cols+c],b); }
  }
}

// stats float layout in ST (floats): see round-5 comment (unchanged)
__global__ void fin_input_k(float* __restrict__ st,
                            const float* __restrict__ cw, const float* __restrict__ cb,
                            const float* __restrict__ vw, const float* __restrict__ vb,
                            const float* __restrict__ ew, const float* __restrict__ eb){
  int t = threadIdx.x;
  if (t < 3){
    float m = st[t]/(float)NCONS, q = st[3+t]/(float)NCONS;
    float A = rsqrtf(fmaxf(q - m*m, 0.f) + 1e-5f)*cw[t];
    st[18+t] = A; st[21+t] = cb[t] - m*A;
  } else if (t < 8){
    int c = t-3;
    float m = st[6+c]/(float)NVARS, q = st[11+c]/(float)NVARS;
    float A = rsqrtf(fmaxf(q - m*m, 0.f) + 1e-5f)*vw[c];
    st[24+c] = A; st[29+c] = vb[c] - m*A;
  } else if (t == 8){
    float m = st[16]/(float)NEDGE, q = st[17]/(float)NEDGE;
    float A = rsqrtf(fmaxf(q - m*m, 0.f) + 1e-5f)*ew[0];
    st[34] = A; st[35] = eb[0] - m*A;
  }
}

// ---- embedding: relu(relu(BN(x)@W1+b1)@W2+b2), block(64)=one node ----
__global__ void embed_k(const float* __restrict__ x, int cin,
                        const float* __restrict__ pA, const float* __restrict__ pB,
                        const float* __restrict__ W1, const float* __restrict__ b1,
                        const float* __restrict__ W2, const float* __restrict__ b2,
                        bf16* __restrict__ out, int nn){
  int n = blockIdx.x; if (n>=nn) return;
  int t = threadIdx.x;
  float acc = b1[t];
  for (int k=0;k<cin;++k){
    float xb = x[n*cin+k]*pA[k] + pB[k];
    acc += xb*W1[k*64+t];
  }
  float h1 = fmaxf(acc, 0.f);
  float acc2 = b2[t];
#pragma unroll
  for (int j=0;j<64;++j) acc2 += shflf(h1,j)*W2[j*64+t];
  out[n*64+t] = __float2bfloat16(fmaxf(acc2, 0.f));
}

// ---- weight fragmenter: f32 row-major [rows][64] -> bf16 MFMA B-fragments
// layout [kc][n][lane][8]; lane holds col=n*16+(lane&15), k=kc*32+(lane>>4)*8+j.
// skiprow>=0: source rows >= skiprow shift by +1 (skip the ef row of W1). ----
__global__ void frag_k(const float* __restrict__ Wsrc, unsigned short* __restrict__ Wdst,
                       int kchunks, int skiprow){
  int i = blockIdx.x*blockDim.x + threadIdx.x;
  int tot = kchunks*4*64*8;
  if (i>=tot) return;
  int j = i & 7, lane = (i>>3)&63, n = (i>>9)&3, kc = i>>11;
  int k = kc*32 + (lane>>4)*8 + j;
  int col = n*16 + (lane&15);
  int srcrow = (skiprow>=0 && k>=skiprow) ? k+1 : k;
  Wdst[i] = f2b(Wsrc[srcrow*64 + col]);
}

// ---- MFMA edge-message kernel: 16 edges per wave-iteration. ----
__global__ void __launch_bounds__(256) msg_mfma_k(
    const bf16* __restrict__ left, const bf16* __restrict__ right,
    const int* __restrict__ src, const int* __restrict__ dst,
    const float* __restrict__ ea, const float* __restrict__ est,
    const unsigned short* __restrict__ W1F, const unsigned short* __restrict__ W2F,
    const float* __restrict__ b1, const float* __restrict__ w1e, const float* __restrict__ b2,
    float* __restrict__ agg)
{
  __shared__ __align__(16) unsigned short w1l[8192];        // 4kc x 4n x 64 x 8
  __shared__ __align__(16) unsigned short w2l[4096];        // 2kc x 4n x 64 x 8
  __shared__ __align__(16) unsigned short h1l[4][16*72];    // per-wave h1 tile, stride 72
  {
    const float4* s1 = (const float4*)W1F; float4* d1 = (float4*)w1l;
    for (int i=threadIdx.x; i<1024; i+=256) d1[i] = s1[i];
    const float4* s2 = (const float4*)W2F; float4* d2 = (float4*)w2l;
    for (int i=threadIdx.x; i<512; i+=256) d2[i] = s2[i];
  }
  __syncthreads();
  const short8v* W1v = (const short8v*)w1l;
  const short8v* W2v = (const short8v*)w2l;
  const unsigned short* rgt = (const unsigned short*)right;
  const unsigned short* lft = (const unsigned short*)left;
  int t = threadIdx.x & 63;
  int wv = threadIdx.x >> 6;
  int gw = (blockIdx.x*blockDim.x + threadIdx.x) >> 6;
  int nw = (gridDim.x*blockDim.x) >> 6;
  int r16 = t & 15, kg = t >> 4;
  float eA = est[0], eB = est[1];
  float bb1[4], we[4], bb2[4];
#pragma unroll
  for (int n=0;n<4;++n){ bb1[n]=b1[n*16+r16]; we[n]=w1e[n*16+r16]; bb2[n]=b2[n*16+r16]; }
  unsigned short* h1w = &h1l[wv][0];

  // NEDGE % 16 == 0: no tail guards needed
  for (int g = gw*16; g < NEDGE; g += nw*16){
    int e = g + r16;
    int dI = dst[e], sI = src[e];
    float ef = ea[e]*eA + eB;
    short8v ar0 = *(const short8v*)(rgt + (size_t)dI*64 + kg*8);
    short8v ar1 = *(const short8v*)(rgt + (size_t)dI*64 + 32 + kg*8);
    short8v al0 = *(const short8v*)(lft + (size_t)sI*64 + kg*8);
    short8v al1 = *(const short8v*)(lft + (size_t)sI*64 + 32 + kg*8);
    float efr[4]; int dIr[4];
#pragma unroll
    for (int r=0;r<4;++r){ efr[r]=shflf(ef, kg*4+r); dIr[r]=__shfl(dI, kg*4+r, 64); }
    float4v c[4];
#pragma unroll
    for (int n=0;n<4;++n){
#pragma unroll
      for (int r=0;r<4;++r) c[n][r] = bb1[n] + efr[r]*we[n];
    }
#pragma unroll
    for (int n=0;n<4;++n){
      c[n] = __builtin_amdgcn_mfma_f32_16x16x32_bf16(ar0, W1v[( 0+n)*64+t], c[n], 0,0,0);
      c[n] = __builtin_amdgcn_mfma_f32_16x16x32_bf16(ar1, W1v[( 4+n)*64+t], c[n], 0,0,0);
      c[n] = __builtin_amdgcn_mfma_f32_16x16x32_bf16(al0, W1v[( 8+n)*64+t], c[n], 0,0,0);
      c[n] = __builtin_amdgcn_mfma_f32_16x16x32_bf16(al1, W1v[(12+n)*64+t], c[n], 0,0,0);
    }
#pragma unroll
    for (int n=0;n<4;++n){
#pragma unroll
      for (int r=0;r<4;++r)
        h1w[(kg*4+r)*72 + n*16 + r16] = f2b(fmaxf(c[n][r], 0.f));
    }
    asm volatile("s_waitcnt lgkmcnt(0)" ::: "memory");
    short8v a20 = *(const short8v*)(h1w + r16*72 + kg*8);
    short8v a21 = *(const short8v*)(h1w + r16*72 + 32 + kg*8);
    float4v d[4];
#pragma unroll
    for (int n=0;n<4;++n) d[n] = (float4v){bb2[n],bb2[n],bb2[n],bb2[n]};
#pragma unroll
    for (int n=0;n<4;++n){
      d[n] = __builtin_amdgcn_mfma_f32_16x16x32_bf16(a20, W2v[(0+n)*64+t], d[n], 0,0,0);
      d[n] = __builtin_amdgcn_mfma_f32_16x16x32_bf16(a21, W2v[(4+n)*64+t], d[n], 0,0,0);
    }
#pragma unroll
    for (int r=0;r<4;++r){
      float* ap = agg + (size_t)dIr[r]*64 + r16;
#pragma unroll
      for (int n=0;n<4;++n) atomicAdd(ap + n*16, d[n][r]);
    }
  }
}

// ---- divide by count in place + column stats of mean-agg ----
__global__ void agg_stats_k(float* __restrict__ agg, const float* __restrict__ cnt,
                            float* __restrict__ slot, int nn){
  int c = threadIdx.x & 63;
  int w = (blockIdx.x*blockDim.x + threadIdx.x) >> 6;
  int nw = (gridDim.x*blockDim.x) >> 6;
  float s=0.f, ss=0.f;
  for (int n=w; n<nn; n+=nw){
    float v = agg[n*64+c] / fmaxf(cnt[n], 1.f);
    agg[n*64+c] = v;
    s += v; ss += v*v;
  }
  atomicAdd(&slot[c], s); atomicAdd(&slot[64+c], ss);
}

__global__ void fin_bn_k(float* __restrict__ slot, const float* __restrict__ w,
                         const float* __restrict__ b, float n){
  int c = threadIdx.x;
  float m = slot[c]/n, q = slot[64+c]/n;
  float rs = rsqrtf(fmaxf(q - m*m, 0.f) + 1e-5f) * w[c];
  slot[128+c] = rs;
  slot[192+c] = b[c] - m*rs;
}

// ---- MFMA node-output MLP: 16 nodes per wave-iteration.
// h1 = relu([BN(agg), right] @ oW1 + ob1); out = h1 @ oW2 + ob2 ----
__global__ void __launch_bounds__(256) node_mfma_k(
    const float* __restrict__ agg, const bf16* __restrict__ right,
    const float* __restrict__ slot,
    const unsigned short* __restrict__ W1F, const unsigned short* __restrict__ W2F,
    const float* __restrict__ b1, const float* __restrict__ b2,
    bf16* __restrict__ out, int nn)
{
  __shared__ __align__(16) unsigned short w1l[8192];
  __shared__ __align__(16) unsigned short w2l[4096];
  __shared__ __align__(16) unsigned short h1l[4][16*72];
  {
    const float4* s1 = (const float4*)W1F; float4* d1 = (float4*)w1l;
    for (int i=threadIdx.x; i<1024; i+=256) d1[i] = s1[i];
    const float4* s2 = (const float4*)W2F; float4* d2 = (float4*)w2l;
    for (int i=threadIdx.x; i<512; i+=256) d2[i] = s2[i];
  }
  __syncthreads();
  const short8v* W1v = (const short8v*)w1l;
  const short8v* W2v = (const short8v*)w2l;
  const unsigned short* rgt = (const unsigned short*)right;
  int t = threadIdx.x & 63;
  int wv = threadIdx.x >> 6;
  int gw = (blockIdx.x*blockDim.x + threadIdx.x) >> 6;
  int nw = (gridDim.x*blockDim.x) >> 6;
  int r16 = t & 15, kg = t >> 4;
  // BN affine consts for lane's k-channels (chunk0: k=kg*8+j, chunk1: k=32+kg*8+j)
  float pA0[8], pB0[8], pA1[8], pB1[8];
#pragma unroll
  for (int j=0;j<8;++j){
    pA0[j]=slot[128+kg*8+j]; pB0[j]=slot[192+kg*8+j];
    pA1[j]=slot[160+kg*8+j]; pB1[j]=slot[224+kg*8+j];
  }
  float bb1[4], bb2[4];
#pragma unroll
  for (int n=0;n<4;++n){ bb1[n]=b1[n*16+r16]; bb2[n]=b2[n*16+r16]; }
  unsigned short* h1w = &h1l[wv][0];

  // nn = 50000, divisible by 16: no tail guards
  for (int g = gw*16; g < nn; g += nw*16){
    int node = g + r16;
    const float* ag = agg + (size_t)node*64;
    float4 f0 = *(const float4*)(ag + kg*8);
    float4 f1 = *(const float4*)(ag + kg*8 + 4);
    float4 f2 = *(const float4*)(ag + 32 + kg*8);
    float4 f3 = *(const float4*)(ag + 32 + kg*8 + 4);
    float v0[8] = {f0.x,f0.y,f0.z,f0.w,f1.x,f1.y,f1.z,f1.w};
    float v1[8] = {f2.x,f2.y,f2.z,f2.w,f3.x,f3.y,f3.z,f3.w};
    short8v ap0, ap1;
#pragma unroll
    for (int j=0;j<8;++j){
      ((unsigned short*)&ap0)[j] = f2b(v0[j]*pA0[j] + pB0[j]);
      ((unsigned short*)&ap1)[j] = f2b(v1[j]*pA1[j] + pB1[j]);
    }
    short8v ar0 = *(const short8v*)(rgt + (size_t)node*64 + kg*8);
    short8v ar1 = *(const short8v*)(rgt + (size_t)node*64 + 32 + kg*8);
    float4v c[4];
#pragma unroll
    for (int n=0;n<4;++n) c[n] = (float4v){bb1[n],bb1[n],bb1[n],bb1[n]};
#pragma unroll
    for (int n=0;n<4;++n){
      c[n] = __builtin_amdgcn_mfma_f32_16x16x32_bf16(ap0, W1v[( 0+n)*64+t], c[n], 0,0,0);
      c[n] = __builtin_amdgcn_mfma_f32_16x16x32_bf16(ap1, W1v[( 4+n)*64+t], c[n], 0,0,0);
      c[n] = __builtin_amdgcn_mfma_f32_16x16x32_bf16(ar0, W1v[( 8+n)*64+t], c[n], 0,0,0);
      c[n] = __builtin_amdgcn_mfma_f32_16x16x32_bf16(ar1, W1v[(12+n)*64+t], c[n], 0,0,0);
    }
#pragma unroll
    for (int n=0;n<4;++n){
#pragma unroll
      for (int r=0;r<4;++r)
        h1w[(kg*4+r)*72 + n*16 + r16] = f2b(fmaxf(c[n][r], 0.f));
    }
    asm volatile("s_waitcnt lgkmcnt(0)" ::: "memory");
    short8v a20 = *(const short8v*)(h1w + r16*72 + kg*8);
    short8v a21 = *(const short8v*)(h1w + r16*72 + 32 + kg*8);
    float4v d[4];
#pragma unroll
    for (int n=0;n<4;++n) d[n] = (float4v){bb2[n],bb2[n],bb2[n],bb2[n]};
#pragma unroll
    for (int n=0;n<4;++n){
      d[n] = __builtin_amdgcn_mfma_f32_16x16x32_bf16(a20, W2v[(0+n)*64+t], d[n], 0,0,0);
      d[n] = __builtin_amdgcn_mfma_f32_16x16x32_bf16(a21, W2v[(4+n)*64+t], d[n], 0,0,0);
    }
    unsigned short* op = (unsigned short*)out;
#pragma unroll
    for (int r=0;r<4;++r){
      size_t base = (size_t)(g + kg*4 + r)*64 + r16;
#pragma unroll
      for (int n=0;n<4;++n) op[base + n*16] = f2b(d[n][r]);
    }
  }
}

// ---- graphnorm stats / finalize / apply ----
__global__ void gn_stats_k(const bf16* __restrict__ x, float* __restrict__ slot, int nn){
  int c = threadIdx.x & 63;
  int w = (blockIdx.x*blockDim.x + threadIdx.x) >> 6;
  int nw = (gridDim.x*blockDim.x) >> 6;
  float s=0.f, ss=0.f;
  for (int n=w;n<nn;n+=nw){ float v=b2f(x[n*64+c]); s+=v; ss+=v*v; }
  atomicAdd(&slot[c],s); atomicAdd(&slot[64+c],ss);
}

__global__ void fin_gn_k(float* __restrict__ slot, const float* __restrict__ w,
                         const float* __restrict__ b, const float* __restrict__ al, float n){
  int c = threadIdx.x;
  float m = slot[c]/n, q = slot[64+c]/n;
  float a = al[c];
  float var = q - 2.f*a*m*m + a*a*m*m;   // E[(x-a*m)^2]
  float A = rsqrtf(fmaxf(var, 0.f) + 1e-5f) * w[c];
  slot[128+c] = A;
  slot[192+c] = b[c] - a*m*A;
}

__global__ void affine_k(bf16* __restrict__ x, const float* __restrict__ slot, int nn){
  int i = blockIdx.x*blockDim.x + threadIdx.x;
  int stride = gridDim.x*blockDim.x;
  int tot = nn*64;
  for (; i<tot; i+=stride){
    int c = i & 63;
    x[i] = __float2bfloat16(b2f(x[i])*slot[128+c] + slot[192+c]);
  }
}

// ---- final MLP: [vf0,vf1,vf2](192) -> 512 -> 128 -> 1 ; 16 nodes/block ----
__global__ void __launch_bounds__(256) final_mlp_k(
    const bf16* __restrict__ vf0, const bf16* __restrict__ vf1, const bf16* __restrict__ vf2,
    const float* __restrict__ W1, const float* __restrict__ B1,
    const float* __restrict__ W2, const float* __restrict__ B2,
    const float* __restrict__ W3, const float* __restrict__ B3,
    void* __restrict__ out, int nn, const int* __restrict__ mode){
  __shared__ __align__(16) float h[16][192];
  __shared__ __align__(16) float h1[16][512];
  __shared__ float h2[16][129];
  int t = threadIdx.x;
  int n0 = blockIdx.x*16;
  for (int i=t; i<16*192; i+=256){
    int n = i/192, j = i - n*192;
    int node = n0+n;
    float v = (j<64) ? b2f(vf0[node*64+j]) : (j<128) ? b2f(vf1[node*64 + (j-64)]) : b2f(vf2[node*64 + (j-128)]);
    h[n][j] = v;
  }
  __syncthreads();
  { // layer 1: cols t and t+256
    float acc0[16], acc1[16];
    float bbA = B1[t], bbB = B1[t+256];
#pragma unroll
    for (int n=0;n<16;++n){ acc0[n]=bbA; acc1[n]=bbB; }
    for (int j4=0;j4<48;++j4){
      float w0[4], w1[4];
#pragma unroll
      for (int q=0;q<4;++q){ w0[q]=W1[(j4*4+q)*512 + t]; w1[q]=W1[(j4*4+q)*512 + t+256]; }
#pragma unroll
      for (int n=0;n<16;++n){
        const float4 hv = *reinterpret_cast<const float4*>(&h[n][j4*4]);
        acc0[n] += hv.x*w0[0]+hv.y*w0[1]+hv.z*w0[2]+hv.w*w0[3];
        acc1[n] += hv.x*w1[0]+hv.y*w1[1]+hv.z*w1[2]+hv.w*w1[3];
      }
    }
#pragma unroll
    for (int n=0;n<16;++n){ h1[n][t]=fmaxf(acc0[n],0.f); h1[n][t+256]=fmaxf(acc1[n],0.f); }
  }
  __syncthreads();
  { // layer 2: col = t&127, node block of 8
    int c = t & 127;
    int nb = (t>>7)*8;
    float acc[8];
    float bb = B2[c];
#pragma unroll
    for (int n=0;n<8;++n) acc[n]=bb;
    for (int j4=0;j4<128;++j4){
      float w[4];
#pragma unroll
      for (int q=0;q<4;++q) w[q]=W2[(j4*4+q)*128 + c];
#pragma unroll
      for (int n=0;n<8;++n){
        const float4 hv = *reinterpret_cast<const float4*>(&h1[nb+n][j4*4]);
        acc[n] += hv.x*w[0]+hv.y*w[1]+hv.z*w[2]+hv.w*w[3];
      }
    }
#pragma unroll
    for (int n=0;n<8;++n) h2[nb+n][c]=fmaxf(acc[n],0.f);
  }
  __syncthreads();
  if (t<16){
    int node = n0+t;
    if (node<nn){
      float acc = B3[0];
      for (int j=0;j<128;++j) acc += h2[t][j]*W3[j];
      if (*mode) ((bf16*)out)[node] = __float2bfloat16(acc);
      else       ((float*)out)[node] = acc;
    }
  }
}

extern "C" void kernel_launch(void* const* d_in, const int* in_sizes, int n_in,
                              void* d_out, int out_size, void* d_ws, size_t ws_size,
                              hipStream_t stream){
  const int* ei = (const int*)d_in[36];
  const int* src_c = ei;            // edge_index[0]: constraint ids
  const int* src_v = ei + NEDGE;    // edge_index[1]: variable ids

  char* ws = (char*)d_ws;
  float* ST = (float*)ws;                       // 4096 floats = 16 KB
  int* MODE = (int*)(ws + 16384);
  // converted-f32 copies of the 36 float inputs, packed after 32 KB (~5.4 MB):
  float* F[36];
  {
    size_t foff = 32768;
    for (int i=0;i<36;++i){ F[i] = (float*)(ws + foff); foff += (size_t)in_sizes[i]*4; }
  }
  // bf16 MFMA weight fragments at 7 MB (192 KB total)
  unsigned short* W1Fb  = (unsigned short*)(ws + 7u*1024*1024);      // 4 x 8192
  unsigned short* W2Fb  = W1Fb + 4*8192;                             // 4 x 4096
  unsigned short* OW1Fb = W2Fb + 4*4096;                             // 4 x 8192
  unsigned short* OW2Fb = OW1Fb + 4*8192;                            // 4 x 4096
  size_t o = 8u*1024*1024;
  float* AGG = (float*)(ws + o); o += (size_t)NCONS*64*sizeof(float);
  float* CNTC = (float*)(ws + o); o += (size_t)NCONS*sizeof(float);
  float* CNTV = (float*)(ws + o); o += (size_t)NVARS*sizeof(float);
  bf16* CFA = (bf16*)(ws + o); o += (size_t)NCONS*64*sizeof(bf16);
  bf16* CFB = (bf16*)(ws + o); o += (size_t)NCONS*64*sizeof(bf16);
  bf16* VF0 = (bf16*)(ws + o); o += (size_t)NVARS*64*sizeof(bf16);
  bf16* VF1 = (bf16*)(ws + o); o += (size_t)NVARS*64*sizeof(bf16);
  bf16* VF2 = (bf16*)(ws + o); o += (size_t)NVARS*64*sizeof(bf16);

  detect_k<<<1,64,0,stream>>>((const unsigned int*)d_in[0], MODE);
  for (int i=0;i<36;++i){
    int n = in_sizes[i];
    int g = (n + 255)/256; if (g > 1024) g = 1024;
    convert_k<<<g,256,0,stream>>>(d_in[i], F[i], n, MODE);
  }
  // pre-fragment conv weights to bf16 MFMA B-layout
  for (int l=0; l<4; ++l){
    frag_k<<<32,256,0,stream>>>(F[17] + (size_t)l*129*64, W1Fb + l*8192, 4, 64);
    frag_k<<<16,256,0,stream>>>(F[19] + (size_t)l*64*64,  W2Fb + l*4096, 2, -1);
    frag_k<<<32,256,0,stream>>>(F[23] + (size_t)l*128*64, OW1Fb + l*8192, 4, -1);
    frag_k<<<16,256,0,stream>>>(F[25] + (size_t)l*64*64,  OW2Fb + l*4096, 2, -1);
  }

  zero_k<<<8,256,0,stream>>>(ST, 4096);
  zero_k<<<128,256,0,stream>>>(CNTC, NCONS + NVARS);   // CNTC,CNTV contiguous
  deg_k<<<1024,256,0,stream>>>(src_c, CNTC);
  deg_k<<<1024,256,0,stream>>>(src_v, CNTV);
  col_stats_k<<<256,256,0,stream>>>(F[0], NCONS, 3, ST+0);
  col_stats_k<<<256,256,0,stream>>>(F[2], NVARS, 5, ST+6);
  col_stats_k<<<512,256,0,stream>>>(F[1], NEDGE, 1, ST+16);
  fin_input_k<<<1,64,0,stream>>>(ST, F[3], F[4], F[11], F[12], F[9], F[10]);
  embed_k<<<NCONS,64,0,stream>>>(F[0], 3, ST+18, ST+21, F[5], F[6], F[7], F[8], CFA, NCONS);
  embed_k<<<NVARS,64,0,stream>>>(F[2], 5, ST+24, ST+29, F[13], F[14], F[15], F[16], VF0, NVARS);

  const bf16* lefts[4]  = {VF0, CFB, VF1, CFA};
  const bf16* rights[4] = {CFA, VF0, CFB, VF1};
  bf16*       outs[4]   = {CFB, VF1, CFA, VF2};
  const int*  srcs[4]   = {src_v, src_c, src_v, src_c};
  const int*  dsts[4]   = {src_c, src_v, src_c, src_v};
  float*      cnts[4]   = {CNTC, CNTV, CNTC, CNTV};

  for (int l=0; l<4; ++l){
    zero_k<<<2048,256,0,stream>>>(AGG, NCONS*64);
    msg_mfma_k<<<1024,256,0,stream>>>(lefts[l], rights[l], srcs[l], dsts[l], F[1], ST+34,
                                      W1Fb + l*8192, W2Fb + l*4096,
                                      F[18] + l*64,
                                      F[17] + (size_t)l*129*64 + 64*64,   // W1 row 64 (ef weights)
                                      F[20] + l*64, AGG);
    float* slot = ST + 36 + l*256;
    agg_stats_k<<<128,256,0,stream>>>(AGG, cnts[l], slot, NCONS);
    fin_bn_k<<<1,64,0,stream>>>(slot, F[21] + l*64, F[22] + l*64, (float)NCONS);
    node_mfma_k<<<512,256,0,stream>>>(AGG, rights[l], slot,
                                      OW1Fb + l*8192, OW2Fb + l*4096,
                                      F[24] + l*64, F[26] + l*64, outs[l], NCONS);
    if (l == 1 || l == 3){
      bf16* cfbuf = outs[l-1];
      bf16* vfbuf = outs[l];
      int ga = l-1, gb = l;
      float* gsA = ST + 36 + 1024 + ga*256;
      float* gsB = ST + 36 + 1024 + gb*256;
      gn_stats_k<<<128,256,0,stream>>>(cfbuf, gsA, NCONS);
      fin_gn_k<<<1,64,0,stream>>>(gsA, F[27]+ga*64, F[28]+ga*64, F[29]+ga*64, (float)NCONS);
      affine_k<<<1024,256,0,stream>>>(cfbuf, gsA, NCONS);
      gn_stats_k<<<128,256,0,stream>>>(vfbuf, gsB, NVARS);
      fin_gn_k<<<1,64,0,stream>>>(gsB, F[27]+gb*64, F[28]+gb*64, F[29]+gb*64, (float)NVARS);
      affine_k<<<1024,256,0,stream>>>(vfbuf, gsB, NVARS);
    }
  }
  final_mlp_k<<<(NVARS+15)/16,256,0,stream>>>(VF0, VF1, VF2, F[30], F[31],
                                              F[32], F[33], F[34], F[35],
                                              d_out, NVARS, MODE);
}

// Round 9
// 1560.397 us; speedup vs baseline: 17.6626x; 1.1610x over previous
//
#include <hip/hip_runtime.h>
#include <hip/hip_bf16.h>

typedef __hip_bfloat16 bf16;
typedef __attribute__((ext_vector_type(8))) short short8v;
typedef __attribute__((ext_vector_type(4))) float float4v;

#define NCONS 50000
#define NVARS 50000
#define NEDGE 600000

__device__ __forceinline__ float b2f(const bf16 v){ return __bfloat162float(v); }
__device__ __forceinline__ float shflf(float v, int lane){ return __shfl(v, lane, 64); }
__device__ __forceinline__ unsigned short f2b(float v){
  return __builtin_bit_cast(unsigned short, __float2bfloat16(v));
}

// ---- input-dtype sniffer (bf16 pairs vs f32) ----
__global__ void detect_k(const unsigned int* __restrict__ x, int* __restrict__ mode){
  int t = threadIdx.x;
  int hits = 0;
  for (int i=0;i<4;++i){
    unsigned w = x[t*4+i];
    unsigned e = (w>>7)&0xFFu;
    if (e >= 0x70u && e <= 0x8Fu) hits++;
  }
  for (int off=32; off>0; off>>=1) hits += __shfl_down(hits, off);
  if (t==0) *mode = (hits > 128) ? 1 : 0;
}

// ---- convert ALL 36 float inputs to f32 workspace in one launch ----
struct CvtArgs { const void* p[36]; int ofs[37]; };
__global__ void convert_all_k(CvtArgs a, float* __restrict__ dst, const int* __restrict__ mode){
  int m = *mode;
  int i = blockIdx.x*blockDim.x + threadIdx.x;
  int stride = gridDim.x*blockDim.x;
  int total = a.ofs[36];
  for (; i<total; i+=stride){
    int s = 0;
#pragma unroll
    for (int k=1;k<36;++k) s += (i >= a.ofs[k]) ? 1 : 0;
    int off = i - a.ofs[s];
    float v;
    if (m) v = b2f(((const bf16*)a.p[s])[off]);
    else   v = ((const float*)a.p[s])[off];
    dst[i] = v;
  }
}

__global__ void zero_k(float* __restrict__ p, int n){
  int i = blockIdx.x*blockDim.x + threadIdx.x;
  int stride = gridDim.x*blockDim.x;
  for (; i<n; i+=stride) p[i] = 0.f;
}

// ---- node degrees, both directions in one launch (cntv = cnt+NCONS) ----
__global__ void deg2_k(const int* __restrict__ ei, float* __restrict__ cnt){
  int i = blockIdx.x*blockDim.x + threadIdx.x;
  int stride = gridDim.x*blockDim.x;
  for (; i<2*NEDGE; i+=stride){
    int id = ei[i];
    atomicAdd(&cnt[(i<NEDGE ? 0 : NCONS) + id], 1.f);
  }
}

// ---- per-column sums / sumsq for BN folding ----
__global__ void col_stats_k(const float* __restrict__ x, int rows, int cols, float* __restrict__ sums){
  int tid = blockIdx.x*blockDim.x + threadIdx.x;
  int stride = gridDim.x*blockDim.x;
  float s[5], ss[5];
  for (int c=0;c<5;++c){ s[c]=0.f; ss[c]=0.f; }
  for (int r=tid; r<rows; r+=stride){
    for (int c=0;c<cols;++c){
      float v = x[r*cols+c];
      s[c]+=v; ss[c]+=v*v;
    }
  }
  for (int c=0;c<cols;++c){
    float a=s[c], b=ss[c];
    for (int off=32; off>0; off>>=1){ a+=__shfl_down(a,off); b+=__shfl_down(b,off); }
    if ((threadIdx.x & 63)==0){ atomicAdd(&sums[c],a); atomicAdd(&sums[cols+c],b); }
  }
}

// stats float layout in ST (floats): see round-5 comment (unchanged)
__global__ void fin_input_k(float* __restrict__ st,
                            const float* __restrict__ cw, const float* __restrict__ cb,
                            const float* __restrict__ vw, const float* __restrict__ vb,
                            const float* __restrict__ ew, const float* __restrict__ eb){
  int t = threadIdx.x;
  if (t < 3){
    float m = st[t]/(float)NCONS, q = st[3+t]/(float)NCONS;
    float A = rsqrtf(fmaxf(q - m*m, 0.f) + 1e-5f)*cw[t];
    st[18+t] = A; st[21+t] = cb[t] - m*A;
  } else if (t < 8){
    int c = t-3;
    float m = st[6+c]/(float)NVARS, q = st[11+c]/(float)NVARS;
    float A = rsqrtf(fmaxf(q - m*m, 0.f) + 1e-5f)*vw[c];
    st[24+c] = A; st[29+c] = vb[c] - m*A;
  } else if (t == 8){
    float m = st[16]/(float)NEDGE, q = st[17]/(float)NEDGE;
    float A = rsqrtf(fmaxf(q - m*m, 0.f) + 1e-5f)*ew[0];
    st[34] = A; st[35] = eb[0] - m*A;
  }
}

// ---- embedding: relu(relu(BN(x)@W1+b1)@W2+b2), block(64)=one node ----
__global__ void embed_k(const float* __restrict__ x, int cin,
                        const float* __restrict__ pA, const float* __restrict__ pB,
                        const float* __restrict__ W1, const float* __restrict__ b1,
                        const float* __restrict__ W2, const float* __restrict__ b2,
                        bf16* __restrict__ out, int nn){
  int n = blockIdx.x; if (n>=nn) return;
  int t = threadIdx.x;
  float acc = b1[t];
  for (int k=0;k<cin;++k){
    float xb = x[n*cin+k]*pA[k] + pB[k];
    acc += xb*W1[k*64+t];
  }
  float h1 = fmaxf(acc, 0.f);
  float acc2 = b2[t];
#pragma unroll
  for (int j=0;j<64;++j) acc2 += shflf(h1,j)*W2[j*64+t];
  out[n*64+t] = __float2bfloat16(fmaxf(acc2, 0.f));
}

// ---- all 16 conv-weight fragment jobs in one launch ----
// per layer l: [0,8192) fm_W1 (skip row 64), [8192,12288) fm_W2,
//              [12288,20480) om_W1, [20480,24576) om_W2
__global__ void frag_all_k(const float* __restrict__ fmW1, const float* __restrict__ fmW2,
                           const float* __restrict__ omW1, const float* __restrict__ omW2,
                           unsigned short* __restrict__ W1Fb, unsigned short* __restrict__ W2Fb,
                           unsigned short* __restrict__ OW1Fb, unsigned short* __restrict__ OW2Fb){
  int i = blockIdx.x*blockDim.x + threadIdx.x;
  if (i >= 4*24576) return;
  int l = i / 24576, r = i % 24576;
  const float* src; unsigned short* dst; int e; int skip;
  if (r < 8192){       src = fmW1 + (size_t)l*129*64; dst = W1Fb  + l*8192; e = r;       skip = 64; }
  else if (r < 12288){ src = fmW2 + (size_t)l*64*64;  dst = W2Fb  + l*4096; e = r-8192;  skip = -1; }
  else if (r < 20480){ src = omW1 + (size_t)l*128*64; dst = OW1Fb + l*8192; e = r-12288; skip = -1; }
  else {               src = omW2 + (size_t)l*64*64;  dst = OW2Fb + l*4096; e = r-20480; skip = -1; }
  int j = e & 7, lane = (e>>3)&63, n = (e>>9)&3, kc = e>>11;
  int k = kc*32 + (lane>>4)*8 + j;
  int col = n*16 + (lane&15);
  int srcrow = (skip>=0 && k>=skip) ? k+1 : k;
  dst[e] = f2b(src[srcrow*64 + col]);
}

// ---- hi/lo fragmenter for final-MLP weights ----
__global__ void frag2_k(const float* __restrict__ Wsrc, unsigned short* __restrict__ Whi,
                        unsigned short* __restrict__ Wlo, int ntiles, int ncols, int tot){
  int i = blockIdx.x*blockDim.x + threadIdx.x;
  if (i>=tot) return;
  int j = i & 7, lane = (i>>3)&63, rem = i>>9;
  int nt = rem % ntiles, kc = rem / ntiles;
  int k = kc*32 + (lane>>4)*8 + j;
  int col = nt*16 + (lane&15);
  float w = Wsrc[k*ncols + col];
  unsigned short hi = f2b(w);
  float rec = __builtin_bit_cast(float, (unsigned int)hi << 16);
  Whi[i] = hi;
  Wlo[i] = f2b(w - rec);
}

// ---- MFMA edge-message kernel: 16 edges per wave-iteration. ----
__global__ void __launch_bounds__(256) msg_mfma_k(
    const bf16* __restrict__ left, const bf16* __restrict__ right,
    const int* __restrict__ src, const int* __restrict__ dst,
    const float* __restrict__ ea, const float* __restrict__ est,
    const unsigned short* __restrict__ W1F, const unsigned short* __restrict__ W2F,
    const float* __restrict__ b1, const float* __restrict__ w1e, const float* __restrict__ b2,
    float* __restrict__ agg)
{
  __shared__ __align__(16) unsigned short w1l[8192];
  __shared__ __align__(16) unsigned short w2l[4096];
  __shared__ __align__(16) unsigned short h1l[4][16*72];
  {
    const float4* s1 = (const float4*)W1F; float4* d1 = (float4*)w1l;
    for (int i=threadIdx.x; i<1024; i+=256) d1[i] = s1[i];
    const float4* s2 = (const float4*)W2F; float4* d2 = (float4*)w2l;
    for (int i=threadIdx.x; i<512; i+=256) d2[i] = s2[i];
  }
  __syncthreads();
  const short8v* W1v = (const short8v*)w1l;
  const short8v* W2v = (const short8v*)w2l;
  const unsigned short* rgt = (const unsigned short*)right;
  const unsigned short* lft = (const unsigned short*)left;
  int t = threadIdx.x & 63;
  int wv = threadIdx.x >> 6;
  int gw = (blockIdx.x*blockDim.x + threadIdx.x) >> 6;
  int nw = (gridDim.x*blockDim.x) >> 6;
  int r16 = t & 15, kg = t >> 4;
  float eA = est[0], eB = est[1];
  float bb1[4], we[4], bb2[4];
#pragma unroll
  for (int n=0;n<4;++n){ bb1[n]=b1[n*16+r16]; we[n]=w1e[n*16+r16]; bb2[n]=b2[n*16+r16]; }
  unsigned short* h1w = &h1l[wv][0];

  for (int g = gw*16; g < NEDGE; g += nw*16){
    int e = g + r16;
    int dI = dst[e], sI = src[e];
    float ef = ea[e]*eA + eB;
    short8v ar0 = *(const short8v*)(rgt + (size_t)dI*64 + kg*8);
    short8v ar1 = *(const short8v*)(rgt + (size_t)dI*64 + 32 + kg*8);
    short8v al0 = *(const short8v*)(lft + (size_t)sI*64 + kg*8);
    short8v al1 = *(const short8v*)(lft + (size_t)sI*64 + 32 + kg*8);
    float efr[4]; int dIr[4];
#pragma unroll
    for (int r=0;r<4;++r){ efr[r]=shflf(ef, kg*4+r); dIr[r]=__shfl(dI, kg*4+r, 64); }
    float4v c[4];
#pragma unroll
    for (int n=0;n<4;++n){
#pragma unroll
      for (int r=0;r<4;++r) c[n][r] = bb1[n] + efr[r]*we[n];
    }
#pragma unroll
    for (int n=0;n<4;++n){
      c[n] = __builtin_amdgcn_mfma_f32_16x16x32_bf16(ar0, W1v[( 0+n)*64+t], c[n], 0,0,0);
      c[n] = __builtin_amdgcn_mfma_f32_16x16x32_bf16(ar1, W1v[( 4+n)*64+t], c[n], 0,0,0);
      c[n] = __builtin_amdgcn_mfma_f32_16x16x32_bf16(al0, W1v[( 8+n)*64+t], c[n], 0,0,0);
      c[n] = __builtin_amdgcn_mfma_f32_16x16x32_bf16(al1, W1v[(12+n)*64+t], c[n], 0,0,0);
    }
#pragma unroll
    for (int n=0;n<4;++n){
#pragma unroll
      for (int r=0;r<4;++r)
        h1w[(kg*4+r)*72 + n*16 + r16] = f2b(fmaxf(c[n][r], 0.f));
    }
    asm volatile("s_waitcnt lgkmcnt(0)" ::: "memory");
    short8v a20 = *(const short8v*)(h1w + r16*72 + kg*8);
    short8v a21 = *(const short8v*)(h1w + r16*72 + 32 + kg*8);
    float4v d[4];
#pragma unroll
    for (int n=0;n<4;++n) d[n] = (float4v){bb2[n],bb2[n],bb2[n],bb2[n]};
#pragma unroll
    for (int n=0;n<4;++n){
      d[n] = __builtin_amdgcn_mfma_f32_16x16x32_bf16(a20, W2v[(0+n)*64+t], d[n], 0,0,0);
      d[n] = __builtin_amdgcn_mfma_f32_16x16x32_bf16(a21, W2v[(4+n)*64+t], d[n], 0,0,0);
    }
#pragma unroll
    for (int r=0;r<4;++r){
      float* ap = agg + (size_t)dIr[r]*64 + r16;
#pragma unroll
      for (int n=0;n<4;++n) atomicAdd(ap + n*16, d[n][r]);
    }
  }
}

// ---- divide by count in place + column stats of mean-agg ----
__global__ void agg_stats_k(float* __restrict__ agg, const float* __restrict__ cnt,
                            float* __restrict__ slot, int nn){
  int c = threadIdx.x & 63;
  int w = (blockIdx.x*blockDim.x + threadIdx.x) >> 6;
  int nw = (gridDim.x*blockDim.x) >> 6;
  float s=0.f, ss=0.f;
  for (int n=w; n<nn; n+=nw){
    float v = agg[n*64+c] / fmaxf(cnt[n], 1.f);
    agg[n*64+c] = v;
    s += v; ss += v*v;
  }
  atomicAdd(&slot[c], s); atomicAdd(&slot[64+c], ss);
}

__global__ void fin_bn_k(float* __restrict__ slot, const float* __restrict__ w,
                         const float* __restrict__ b, float n){
  int c = threadIdx.x;
  float m = slot[c]/n, q = slot[64+c]/n;
  float rs = rsqrtf(fmaxf(q - m*m, 0.f) + 1e-5f) * w[c];
  slot[128+c] = rs;
  slot[192+c] = b[c] - m*rs;
}

// ---- MFMA node-output MLP: 16 nodes per wave-iteration. ----
__global__ void __launch_bounds__(256) node_mfma_k(
    const float* __restrict__ agg, const bf16* __restrict__ right,
    const float* __restrict__ slot,
    const unsigned short* __restrict__ W1F, const unsigned short* __restrict__ W2F,
    const float* __restrict__ b1, const float* __restrict__ b2,
    bf16* __restrict__ out, int nn)
{
  __shared__ __align__(16) unsigned short w1l[8192];
  __shared__ __align__(16) unsigned short w2l[4096];
  __shared__ __align__(16) unsigned short h1l[4][16*72];
  {
    const float4* s1 = (const float4*)W1F; float4* d1 = (float4*)w1l;
    for (int i=threadIdx.x; i<1024; i+=256) d1[i] = s1[i];
    const float4* s2 = (const float4*)W2F; float4* d2 = (float4*)w2l;
    for (int i=threadIdx.x; i<512; i+=256) d2[i] = s2[i];
  }
  __syncthreads();
  const short8v* W1v = (const short8v*)w1l;
  const short8v* W2v = (const short8v*)w2l;
  const unsigned short* rgt = (const unsigned short*)right;
  int t = threadIdx.x & 63;
  int wv = threadIdx.x >> 6;
  int gw = (blockIdx.x*blockDim.x + threadIdx.x) >> 6;
  int nw = (gridDim.x*blockDim.x) >> 6;
  int r16 = t & 15, kg = t >> 4;
  float pA0[8], pB0[8], pA1[8], pB1[8];
#pragma unroll
  for (int j=0;j<8;++j){
    pA0[j]=slot[128+kg*8+j]; pB0[j]=slot[192+kg*8+j];
    pA1[j]=slot[160+kg*8+j]; pB1[j]=slot[224+kg*8+j];
  }
  float bb1[4], bb2[4];
#pragma unroll
  for (int n=0;n<4;++n){ bb1[n]=b1[n*16+r16]; bb2[n]=b2[n*16+r16]; }
  unsigned short* h1w = &h1l[wv][0];

  for (int g = gw*16; g < nn; g += nw*16){
    int node = g + r16;
    const float* ag = agg + (size_t)node*64;
    float4 f0 = *(const float4*)(ag + kg*8);
    float4 f1 = *(const float4*)(ag + kg*8 + 4);
    float4 f2 = *(const float4*)(ag + 32 + kg*8);
    float4 f3 = *(const float4*)(ag + 32 + kg*8 + 4);
    float v0[8] = {f0.x,f0.y,f0.z,f0.w,f1.x,f1.y,f1.z,f1.w};
    float v1[8] = {f2.x,f2.y,f2.z,f2.w,f3.x,f3.y,f3.z,f3.w};
    short8v ap0, ap1;
#pragma unroll
    for (int j=0;j<8;++j){
      ((unsigned short*)&ap0)[j] = f2b(v0[j]*pA0[j] + pB0[j]);
      ((unsigned short*)&ap1)[j] = f2b(v1[j]*pA1[j] + pB1[j]);
    }
    short8v ar0 = *(const short8v*)(rgt + (size_t)node*64 + kg*8);
    short8v ar1 = *(const short8v*)(rgt + (size_t)node*64 + 32 + kg*8);
    float4v c[4];
#pragma unroll
    for (int n=0;n<4;++n) c[n] = (float4v){bb1[n],bb1[n],bb1[n],bb1[n]};
#pragma unroll
    for (int n=0;n<4;++n){
      c[n] = __builtin_amdgcn_mfma_f32_16x16x32_bf16(ap0, W1v[( 0+n)*64+t], c[n], 0,0,0);
      c[n] = __builtin_amdgcn_mfma_f32_16x16x32_bf16(ap1, W1v[( 4+n)*64+t], c[n], 0,0,0);
      c[n] = __builtin_amdgcn_mfma_f32_16x16x32_bf16(ar0, W1v[( 8+n)*64+t], c[n], 0,0,0);
      c[n] = __builtin_amdgcn_mfma_f32_16x16x32_bf16(ar1, W1v[(12+n)*64+t], c[n], 0,0,0);
    }
#pragma unroll
    for (int n=0;n<4;++n){
#pragma unroll
      for (int r=0;r<4;++r)
        h1w[(kg*4+r)*72 + n*16 + r16] = f2b(fmaxf(c[n][r], 0.f));
    }
    asm volatile("s_waitcnt lgkmcnt(0)" ::: "memory");
    short8v a20 = *(const short8v*)(h1w + r16*72 + kg*8);
    short8v a21 = *(const short8v*)(h1w + r16*72 + 32 + kg*8);
    float4v d[4];
#pragma unroll
    for (int n=0;n<4;++n) d[n] = (float4v){bb2[n],bb2[n],bb2[n],bb2[n]};
#pragma unroll
    for (int n=0;n<4;++n){
      d[n] = __builtin_amdgcn_mfma_f32_16x16x32_bf16(a20, W2v[(0+n)*64+t], d[n], 0,0,0);
      d[n] = __builtin_amdgcn_mfma_f32_16x16x32_bf16(a21, W2v[(4+n)*64+t], d[n], 0,0,0);
    }
    unsigned short* op = (unsigned short*)out;
#pragma unroll
    for (int r=0;r<4;++r){
      size_t base = (size_t)(g + kg*4 + r)*64 + r16;
#pragma unroll
      for (int n=0;n<4;++n) op[base + n*16] = f2b(d[n][r]);
    }
  }
}

// ---- graphnorm stats / finalize / apply ----
__global__ void gn_stats_k(const bf16* __restrict__ x, float* __restrict__ slot, int nn){
  int c = threadIdx.x & 63;
  int w = (blockIdx.x*blockDim.x + threadIdx.x) >> 6;
  int nw = (gridDim.x*blockDim.x) >> 6;
  float s=0.f, ss=0.f;
  for (int n=w;n<nn;n+=nw){ float v=b2f(x[n*64+c]); s+=v; ss+=v*v; }
  atomicAdd(&slot[c],s); atomicAdd(&slot[64+c],ss);
}

__global__ void fin_gn_k(float* __restrict__ slot, const float* __restrict__ w,
                         const float* __restrict__ b, const float* __restrict__ al, float n){
  int c = threadIdx.x;
  float m = slot[c]/n, q = slot[64+c]/n;
  float a = al[c];
  float var = q - 2.f*a*m*m + a*a*m*m;
  float A = rsqrtf(fmaxf(var, 0.f) + 1e-5f) * w[c];
  slot[128+c] = A;
  slot[192+c] = b[c] - a*m*A;
}

__global__ void affine_k(bf16* __restrict__ x, const float* __restrict__ slot, int nn){
  int i = blockIdx.x*blockDim.x + threadIdx.x;
  int stride = gridDim.x*blockDim.x;
  int tot = nn*64;
  for (; i<tot; i+=stride){
    int c = i & 63;
    x[i] = __float2bfloat16(b2f(x[i])*slot[128+c] + slot[192+c]);
  }
}

// ---- MFMA final MLP, race-free: ONE 16-node tile per wave, straight-line
// control flow, real __syncthreads() between h1 LDS writes and reads. ----
__global__ void __launch_bounds__(256) final_mfma_k(
    const bf16* __restrict__ vf0, const bf16* __restrict__ vf1, const bf16* __restrict__ vf2,
    const unsigned short* __restrict__ W1hi, const unsigned short* __restrict__ W1lo,
    const unsigned short* __restrict__ W2hi, const unsigned short* __restrict__ W2lo,
    const float* __restrict__ B1, const float* __restrict__ B2,
    const float* __restrict__ W3, const float* __restrict__ B3,
    void* __restrict__ out, int nn, const int* __restrict__ mode)
{
  __shared__ float h1l[4][16*260];   // per-wave 16x256 f32 tile, stride 260
  const short8v* W1h = (const short8v*)W1hi;
  const short8v* W1l = (const short8v*)W1lo;
  const short8v* W2h = (const short8v*)W2hi;
  const short8v* W2l = (const short8v*)W2lo;
  const unsigned short* v0p = (const unsigned short*)vf0;
  const unsigned short* v1p = (const unsigned short*)vf1;
  const unsigned short* v2p = (const unsigned short*)vf2;
  int t = threadIdx.x & 63;
  int wv = threadIdx.x >> 6;
  int r16 = t & 15, kg = t >> 4;
  int tile = blockIdx.x*4 + wv;          // grid sized so tiles*16 covers nn
  bool act = (tile*16 < nn);
  int g = act ? tile*16 : 0;             // inactive waves compute on tile 0, never write
  float* h1w = &h1l[wv][0];
  float b2v[8], w3v[8];
#pragma unroll
  for (int n=0;n<8;++n){ b2v[n] = B2[n*16+r16]; w3v[n] = W3[n*16+r16]; }
  float bb3 = B3[0];
  int md = *mode;

  int node = g + r16;
  short8v A1[6];
  A1[0] = *(const short8v*)(v0p + (size_t)node*64 + kg*8);
  A1[1] = *(const short8v*)(v0p + (size_t)node*64 + 32 + kg*8);
  A1[2] = *(const short8v*)(v1p + (size_t)node*64 + kg*8);
  A1[3] = *(const short8v*)(v1p + (size_t)node*64 + 32 + kg*8);
  A1[4] = *(const short8v*)(v2p + (size_t)node*64 + kg*8);
  A1[5] = *(const short8v*)(v2p + (size_t)node*64 + 32 + kg*8);
  float4v D[8];
#pragma unroll
  for (int n=0;n<8;++n) D[n] = (float4v){b2v[n],b2v[n],b2v[n],b2v[n]};

  for (int half=0; half<2; ++half){
    if (half) __syncthreads();           // drain half-0 reads before overwrite
    // layer 1: this half's 256 output columns, K=192, W = hi+lo
    for (int nt=0; nt<16; ++nt){
      int ntg = half*16 + nt;
      float bb = B1[ntg*16 + r16];
      float4v C = (float4v){bb,bb,bb,bb};
#pragma unroll
      for (int kc=0; kc<6; ++kc){
        C = __builtin_amdgcn_mfma_f32_16x16x32_bf16(A1[kc], W1h[(kc*32+ntg)*64+t], C, 0,0,0);
        C = __builtin_amdgcn_mfma_f32_16x16x32_bf16(A1[kc], W1l[(kc*32+ntg)*64+t], C, 0,0,0);
      }
#pragma unroll
      for (int r=0;r<4;++r)
        h1w[(kg*4+r)*260 + nt*16 + r16] = fmaxf(C[r], 0.f);
    }
    __syncthreads();                     // h1 writes visible before transpose read
    short8v Ahi[8], Alo[8];
#pragma unroll
    for (int kc=0; kc<8; ++kc){
      const float* hp = h1w + r16*260 + kc*32 + kg*8;
      float4 x0 = *(const float4*)(hp);
      float4 x1 = *(const float4*)(hp+4);
      float vv[8] = {x0.x,x0.y,x0.z,x0.w,x1.x,x1.y,x1.z,x1.w};
#pragma unroll
      for (int j=0;j<8;++j){
        unsigned short hi = f2b(vv[j]);
        float rec = __builtin_bit_cast(float, (unsigned int)hi<<16);
        ((unsigned short*)&Ahi[kc])[j] = hi;
        ((unsigned short*)&Alo[kc])[j] = f2b(vv[j] - rec);
      }
    }
    // layer 2: K-half of 256, Ahi@Whi + Alo@Whi + Ahi@Wlo
#pragma unroll
    for (int nt2=0; nt2<8; ++nt2){
#pragma unroll
      for (int kc=0; kc<8; ++kc){
        int kcg = half*8 + kc;
        short8v bh = W2h[(kcg*8+nt2)*64+t];
        D[nt2] = __builtin_amdgcn_mfma_f32_16x16x32_bf16(Ahi[kc], bh, D[nt2], 0,0,0);
        D[nt2] = __builtin_amdgcn_mfma_f32_16x16x32_bf16(Alo[kc], bh, D[nt2], 0,0,0);
        D[nt2] = __builtin_amdgcn_mfma_f32_16x16x32_bf16(Ahi[kc], W2l[(kcg*8+nt2)*64+t], D[nt2], 0,0,0);
      }
    }
  }
  // layer 3: relu(h2) . W3 in f32, 16-lane tree reduction
  float part[4] = {0.f,0.f,0.f,0.f};
#pragma unroll
  for (int n=0;n<8;++n){
#pragma unroll
    for (int r=0;r<4;++r) part[r] += fmaxf(D[n][r],0.f)*w3v[n];
  }
#pragma unroll
  for (int r=0;r<4;++r){
#pragma unroll
    for (int off=1; off<16; off<<=1) part[r] += __shfl_xor(part[r], off, 64);
  }
  if (act && r16==0){
#pragma unroll
    for (int r=0;r<4;++r){
      int node_o = g + kg*4 + r;
      float val = part[r] + bb3;
      if (md) ((bf16*)out)[node_o] = __float2bfloat16(val);
      else    ((float*)out)[node_o] = val;
    }
  }
}

extern "C" void kernel_launch(void* const* d_in, const int* in_sizes, int n_in,
                              void* d_out, int out_size, void* d_ws, size_t ws_size,
                              hipStream_t stream){
  const int* ei = (const int*)d_in[36];
  const int* src_c = ei;            // edge_index[0]: constraint ids
  const int* src_v = ei + NEDGE;    // edge_index[1]: variable ids

  char* ws = (char*)d_ws;
  float* ST = (float*)ws;                       // 4096 floats = 16 KB
  int* MODE = (int*)(ws + 16384);
  float* FBASE = (float*)(ws + 32768);
  CvtArgs ca;
  float* F[36];
  {
    int off = 0;
    for (int i=0;i<36;++i){
      ca.p[i] = d_in[i];
      ca.ofs[i] = off;
      F[i] = FBASE + off;
      off += in_sizes[i];
    }
    ca.ofs[36] = off;
  }
  // bf16 MFMA weight fragments at 7 MB
  unsigned short* W1Fb  = (unsigned short*)(ws + 7u*1024*1024);      // 4 x 8192
  unsigned short* W2Fb  = W1Fb + 4*8192;                             // 4 x 4096
  unsigned short* OW1Fb = W2Fb + 4*4096;                             // 4 x 8192
  unsigned short* OW2Fb = OW1Fb + 4*8192;                            // 4 x 4096
  unsigned short* FW1H  = OW2Fb + 4*4096;                            // 98304
  unsigned short* FW1L  = FW1H + 98304;                              // 98304
  unsigned short* FW2H  = FW1L + 98304;                              // 65536
  unsigned short* FW2L  = FW2H + 65536;                              // 65536
  size_t o = 8u*1024*1024;
  float* AGG = (float*)(ws + o); o += (size_t)NCONS*64*sizeof(float);
  float* CNTC = (float*)(ws + o); o += (size_t)NCONS*sizeof(float);
  float* CNTV = (float*)(ws + o); o += (size_t)NVARS*sizeof(float);
  bf16* CFA = (bf16*)(ws + o); o += (size_t)NCONS*64*sizeof(bf16);
  bf16* CFB = (bf16*)(ws + o); o += (size_t)NCONS*64*sizeof(bf16);
  bf16* VF0 = (bf16*)(ws + o); o += (size_t)NVARS*64*sizeof(bf16);
  bf16* VF1 = (bf16*)(ws + o); o += (size_t)NVARS*64*sizeof(bf16);
  bf16* VF2 = (bf16*)(ws + o); o += (size_t)NVARS*64*sizeof(bf16);

  detect_k<<<1,64,0,stream>>>((const unsigned int*)d_in[0], MODE);
  convert_all_k<<<2048,256,0,stream>>>(ca, FBASE, MODE);
  frag_all_k<<<384,256,0,stream>>>(F[17], F[19], F[23], F[25], W1Fb, W2Fb, OW1Fb, OW2Fb);
  frag2_k<<<384,256,0,stream>>>(F[30], FW1H, FW1L, 32, 512, 98304);
  frag2_k<<<256,256,0,stream>>>(F[32], FW2H, FW2L, 8, 128, 65536);

  zero_k<<<8,256,0,stream>>>(ST, 4096);
  zero_k<<<128,256,0,stream>>>(CNTC, NCONS + NVARS);   // CNTC,CNTV contiguous
  deg2_k<<<1024,256,0,stream>>>(ei, CNTC);
  col_stats_k<<<256,256,0,stream>>>(F[0], NCONS, 3, ST+0);
  col_stats_k<<<256,256,0,stream>>>(F[2], NVARS, 5, ST+6);
  col_stats_k<<<512,256,0,stream>>>(F[1], NEDGE, 1, ST+16);
  fin_input_k<<<1,64,0,stream>>>(ST, F[3], F[4], F[11], F[12], F[9], F[10]);
  embed_k<<<NCONS,64,0,stream>>>(F[0], 3, ST+18, ST+21, F[5], F[6], F[7], F[8], CFA, NCONS);
  embed_k<<<NVARS,64,0,stream>>>(F[2], 5, ST+24, ST+29, F[13], F[14], F[15], F[16], VF0, NVARS);

  const bf16* lefts[4]  = {VF0, CFB, VF1, CFA};
  const bf16* rights[4] = {CFA, VF0, CFB, VF1};
  bf16*       outs[4]   = {CFB, VF1, CFA, VF2};
  const int*  srcs[4]   = {src_v, src_c, src_v, src_c};
  const int*  dsts[4]   = {src_c, src_v, src_c, src_v};
  float*      cnts[4]   = {CNTC, CNTV, CNTC, CNTV};

  for (int l=0; l<4; ++l){
    zero_k<<<2048,256,0,stream>>>(AGG, NCONS*64);
    msg_mfma_k<<<1024,256,0,stream>>>(lefts[l], rights[l], srcs[l], dsts[l], F[1], ST+34,
                                      W1Fb + l*8192, W2Fb + l*4096,
                                      F[18] + l*64,
                                      F[17] + (size_t)l*129*64 + 64*64,
                                      F[20] + l*64, AGG);
    float* slot = ST + 36 + l*256;
    agg_stats_k<<<128,256,0,stream>>>(AGG, cnts[l], slot, NCONS);
    fin_bn_k<<<1,64,0,stream>>>(slot, F[21] + l*64, F[22] + l*64, (float)NCONS);
    node_mfma_k<<<512,256,0,stream>>>(AGG, rights[l], slot,
                                      OW1Fb + l*8192, OW2Fb + l*4096,
                                      F[24] + l*64, F[26] + l*64, outs[l], NCONS);
    if (l == 1 || l == 3){
      bf16* cfbuf = outs[l-1];
      bf16* vfbuf = outs[l];
      int ga = l-1, gb = l;
      float* gsA = ST + 36 + 1024 + ga*256;
      float* gsB = ST + 36 + 1024 + gb*256;
      gn_stats_k<<<128,256,0,stream>>>(cfbuf, gsA, NCONS);
      fin_gn_k<<<1,64,0,stream>>>(gsA, F[27]+ga*64, F[28]+ga*64, F[29]+ga*64, (float)NCONS);
      affine_k<<<1024,256,0,stream>>>(cfbuf, gsA, NCONS);
      gn_stats_k<<<128,256,0,stream>>>(vfbuf, gsB, NVARS);
      fin_gn_k<<<1,64,0,stream>>>(gsB, F[27]+gb*64, F[28]+gb*64, F[29]+gb*64, (float)NVARS);
      affine_k<<<1024,256,0,stream>>>(vfbuf, gsB, NVARS);
    }
  }
  // 3125 tiles of 16 nodes; 4 tiles per 256-thread block -> 782 blocks
  final_mfma_k<<<782,256,0,stream>>>(VF0, VF1, VF2,
                                     FW1H, FW1L, FW2H, FW2L,
                                     F[31], F[33], F[34], F[35],
                                     d_out, NVARS, MODE);
}